// Round 18
// baseline (227.425 us; speedup 1.0000x reference)
//
#include <hip/hip_runtime.h>
#include <cstdint>

#define HB 2
#define HS 1024
#define HSF 2048
#define HH 16
#define HDH 128
#define HD 2048
#define HD3 6144
#define HM 2048  // HB*HS

typedef __attribute__((ext_vector_type(8))) short bf16x8;
typedef __attribute__((ext_vector_type(4))) float f32x4;
typedef __attribute__((ext_vector_type(16))) float f32x16;
typedef unsigned short u16;
typedef unsigned int u32;

__device__ __forceinline__ u16 f2b(float f) {
    union { float f; u32 u; } v; v.f = f;
    u32 u = v.u;
    return (u16)((u + 0x7FFFu + ((u >> 16) & 1u)) >> 16);
}
__device__ __forceinline__ float b2f(u16 h) {
    union { u32 u; float f; } v; v.u = ((u32)h) << 16; return v.f;
}

__device__ __forceinline__ f32x4 mfma16x16(bf16x8 a, bf16x8 b, f32x4 c) {
    return __builtin_amdgcn_mfma_f32_16x16x32_bf16(a, b, c, 0, 0, 0);
}
__device__ __forceinline__ f32x16 mfma32x32(bf16x8 a, bf16x8 b, f32x16 c) {
    return __builtin_amdgcn_mfma_f32_32x32x16_bf16(a, b, c, 0, 0, 0);
}
__device__ __forceinline__ void pl32swap(u32 &a, u32 &b) {
    asm volatile("v_permlane32_swap_b32 %0, %1" : "+v"(a), "+v"(b));
}

#define GLD16(gp, lp) __builtin_amdgcn_global_load_lds( \
    (__attribute__((address_space(1))) void*)(gp), \
    (__attribute__((address_space(3))) void*)(lp), 16, 0, 0)

// ---------------- fused streaming prep (r13-proven) ----------------
__global__ __launch_bounds__(256) void k_prep(
    const float* __restrict__ x,  u16* __restrict__ xb,  int n0,
    const float* __restrict__ qkv, u16* __restrict__ qkvb, int n1,
    const float* __restrict__ wo,  u16* __restrict__ wob, int n2,
    const float* __restrict__ kc, const float* __restrict__ vc,
    float* __restrict__ kf, float* __restrict__ vf,
    u16* __restrict__ kb, u16* __restrict__ vt)
{
    const int bid = blockIdx.x;
    const int tid = threadIdx.x;
    if (bid < 512) {
        __shared__ u16 Lt[128 * 66];      // [dh][s] — stride 66
        int bh = bid >> 4, st = (bid & 15) << 6;
        size_t cbase = (size_t)bh * (HS * HDH) + (size_t)st * HDH;
        size_t fbase = (size_t)bh * (HSF * HDH) + (size_t)st * HDH;
        #pragma unroll
        for (int i = 0; i < 8; ++i) {
            int ci = i * 256 + tid;
            float4 kv = ((const float4*)(kc + cbase))[ci];
            ((float4*)(kf + fbase))[ci] = kv;
            ushort4 k4;
            k4.x = f2b(kv.x); k4.y = f2b(kv.y); k4.z = f2b(kv.z); k4.w = f2b(kv.w);
            ((ushort4*)(kb + fbase))[ci] = k4;
        }
        #pragma unroll
        for (int i = 0; i < 8; ++i) {
            int ci = i * 256 + tid;
            int r = ci >> 5, c = ci & 31;
            float4 vv = ((const float4*)(vc + cbase))[ci];
            ((float4*)(vf + fbase))[ci] = vv;
            int dh = c * 4;
            Lt[(dh + 0) * 66 + r] = f2b(vv.x);
            Lt[(dh + 1) * 66 + r] = f2b(vv.y);
            Lt[(dh + 2) * 66 + r] = f2b(vv.z);
            Lt[(dh + 3) * 66 + r] = f2b(vv.w);
        }
        __syncthreads();
        u16* vtb = vt + (size_t)bh * (HDH * HSF) + st;
        #pragma unroll
        for (int i = 0; i < 4; ++i) {
            int ci = i * 256 + tid;
            int dh = ci >> 3, cs = (ci & 7) * 8;
            const u16* lr = &Lt[dh * 66 + cs];
            ushort4 lo, hi2;
            lo.x = lr[0]; lo.y = lr[1]; lo.z = lr[2]; lo.w = lr[3];
            hi2.x = lr[4]; hi2.y = lr[5]; hi2.z = lr[6]; hi2.w = lr[7];
            u16* dst = vtb + (size_t)dh * HSF + cs;
            *(ushort4*)dst = lo;
            *(ushort4*)(dst + 4) = hi2;
        }
    } else {
        int i = (bid - 512) * 256 + tid;
        const int st_ = ((int)gridDim.x - 512) * 256;
        const int nt = n0 + n1 + n2;
        for (; i < nt; i += st_) {
            const float* s; u16* d; int j = i;
            if (j < n0) { s = x; d = xb; }
            else if (j < n0 + n1) { j -= n0; s = qkv; d = qkvb; }
            else { j -= n0 + n1; s = wo; d = wob; }
            float4 v = ((const float4*)s)[j];
            ushort4 o;
            o.x = f2b(v.x); o.y = f2b(v.y); o.z = f2b(v.z); o.w = f2b(v.w);
            ((ushort4*)d)[j] = o;
        }
    }
}

// ---------------- QKV GEMM: 128x128 tile, BK=32, 2-phase dbuf (r17-proven) ----------------
__global__ __launch_bounds__(256, 2) void k_gemm_qkv(
    const u16* __restrict__ A, const u16* __restrict__ Bw, int K,
    u16* __restrict__ qb, float* __restrict__ kf, float* __restrict__ vf,
    u16* __restrict__ kb, u16* __restrict__ vt)
{
    __shared__ __align__(16) u16 SH[16384];   // As = SH[0..8191], Bs = SH[8192..]
    u16* As = SH;
    u16* Bs = SH + 8192;
    const int tid = threadIdx.x;
    const int w = tid >> 6, lane = tid & 63;
    const int wm = w >> 1, wn = w & 1;
    const int lcol = lane & 15, lhi = lane >> 4;

    const int nb = (int)gridDim.x, per = nb >> 3;
    const int bf = (int)blockIdx.x;
    const int t = (bf & 7) * per + (bf >> 3);
    const int m0 = (t & 15) * 128, n0 = (t >> 4) * 128;

    const int srow = lane >> 2;
    const int scol = ((lane & 3) ^ ((lane >> 4) & 2)) * 8;  // pre-swizzled source chunk
    const int c0 = w * 2, c1 = w * 2 + 1;
    const u16* Ag0 = A + (size_t)(m0 + c0 * 16 + srow) * K + scol;
    const u16* Ag1 = A + (size_t)(m0 + c1 * 16 + srow) * K + scol;
    const u16* Bg0 = Bw + (size_t)(n0 + c0 * 16 + srow) * K + scol;
    const u16* Bg1 = Bw + (size_t)(n0 + c1 * 16 + srow) * K + scol;

    const int lx = lhi ^ ((lcol >> 2) & 2);            // swizzled read chunk

    f32x4 acc[4][4] = {};

    GLD16(Ag0, &As[c0 * 512]);
    GLD16(Ag1, &As[c1 * 512]);
    GLD16(Bg0, &Bs[c0 * 512]);
    GLD16(Bg1, &Bs[c1 * 512]);
    __syncthreads();

    int cur = 0;
    for (int k0 = 0; k0 < K; k0 += 32) {
        if (k0 + 32 < K) {
            int nb_ = (cur ^ 1) * 4096;
            GLD16(Ag0 + k0 + 32, &As[nb_ + c0 * 512]);
            GLD16(Ag1 + k0 + 32, &As[nb_ + c1 * 512]);
            GLD16(Bg0 + k0 + 32, &Bs[nb_ + c0 * 512]);
            GLD16(Bg1 + k0 + 32, &Bs[nb_ + c1 * 512]);
        }
        const int cb = cur * 4096;
        bf16x8 af[4], bfr[4];
        #pragma unroll
        for (int i = 0; i < 4; ++i)
            af[i] = *(const bf16x8*)&As[cb + (wm * 64 + i * 16 + lcol) * 32 + lx * 8];
        #pragma unroll
        for (int i = 0; i < 4; ++i)
            bfr[i] = *(const bf16x8*)&Bs[cb + (wn * 64 + i * 16 + lcol) * 32 + lx * 8];
        __builtin_amdgcn_s_setprio(1);
        #pragma unroll
        for (int i = 0; i < 4; ++i)
            #pragma unroll
            for (int j = 0; j < 4; ++j)
                acc[i][j] = mfma16x16(af[i], bfr[j], acc[i][j]);
        __builtin_amdgcn_s_setprio(0);
        __syncthreads();
        cur ^= 1;
    }

    const int bsec = n0 >> 11;               // block-uniform section (0=Q,1=K,2=V)
    if (bsec == 2) {
        // ---- V block: vf scatter + LDS-transposed coalesced vt ----
        u16* T = SH;                         // 128x128 u16, XOR-swizzled columns
        #pragma unroll
        for (int i = 0; i < 4; ++i) {
          #pragma unroll
          for (int j = 0; j < 4; ++j) {
            #pragma unroll
            for (int r = 0; r < 4; ++r) {
                int sl = wm * 64 + i * 16 + lhi * 4 + r;     // local s (m)
                int dl = wn * 64 + j * 16 + lcol;            // local dh (n)
                int m = m0 + sl, n = n0 + dl;
                float v = acc[i][j][r];
                int b = m >> 10, s = m & 1023;
                int e = n & 2047;
                int h = e >> 7, dh = e & 127;
                int bh = b * HH + h;
                vf[((size_t)bh * HSF + HS + s) * HDH + dh] = v;
                T[dl * 128 + (sl ^ ((dl & 15) << 3))] = f2b(v);
            }
          }
        }
        __syncthreads();
        const int b2 = m0 >> 10, s0 = m0 & 1023;
        const int hh = (n0 & 2047) >> 7;
        const int bh2 = b2 * HH + hh;
        u16* vtb = vt + (size_t)(bh2 * HDH) * HSF + HS + s0;
        #pragma unroll
        for (int it = 0; it < 8; ++it) {
            int ci = it * 256 + tid;                 // 0..2047 chunks of 8
            int dl = ci >> 4, ch = ci & 15;
            const u16* lr = &T[dl * 128 + ((ch * 8) ^ ((dl & 15) << 3))];
            ushort4 lo = *(const ushort4*)lr;
            ushort4 hi2 = *(const ushort4*)(lr + 4);
            u16* dst = vtb + (size_t)dl * HSF + ch * 8;
            *(ushort4*)dst = lo;
            *(ushort4*)(dst + 4) = hi2;
        }
    } else {
        #pragma unroll
        for (int i = 0; i < 4; ++i) {
          #pragma unroll
          for (int j = 0; j < 4; ++j) {
            #pragma unroll
            for (int r = 0; r < 4; ++r) {
                int m = m0 + wm * 64 + i * 16 + lhi * 4 + r;
                int n = n0 + wn * 64 + j * 16 + lcol;
                float v = acc[i][j][r];
                int b = m >> 10, s = m & 1023;
                int e = n & 2047;
                int h = e >> 7, dh = e & 127;
                int bh = b * HH + h;
                if (bsec == 0) {
                    // pre-scale Q by 1/sqrt(dh) * log2(e) for exp2-domain softmax
                    qb[((size_t)bh * HS + s) * HDH + dh] = f2b(v * 0.12751742f);
                } else {
                    size_t idx = ((size_t)bh * HSF + HS + s) * HDH + dh;
                    kf[idx] = v; kb[idx] = f2b(v);
                }
            }
          }
        }
    }
}

// ---------------- output GEMM: 128x64 tile, BK=32, 2-phase dbuf (r14-proven) ----------------
__global__ __launch_bounds__(256, 4) void k_gemm_out(
    const u16* __restrict__ A, const u16* __restrict__ Bw, int K,
    float* __restrict__ outf)
{
    __shared__ __align__(16) u16 As[2 * 128 * 32];   // 16 KB
    __shared__ __align__(16) u16 Bs[2 * 64 * 32];    // 8 KB
    const int tid = threadIdx.x;
    const int w = tid >> 6, lane = tid & 63;
    const int wm = w >> 1, wn = w & 1;
    const int lcol = lane & 15, lhi = lane >> 4;

    const int nb = (int)gridDim.x, per = nb >> 3;
    const int bf = (int)blockIdx.x;
    const int t = (bf & 7) * per + (bf >> 3);
    const int m0 = (t & 15) * 128, n0 = (t >> 4) * 64;

    const int srow = lane >> 2;
    const int scol = ((lane & 3) ^ ((lane >> 4) & 2)) * 8;
    const int c0 = w * 2, c1 = w * 2 + 1;
    const u16* Ag0 = A + (size_t)(m0 + c0 * 16 + srow) * K + scol;
    const u16* Ag1 = A + (size_t)(m0 + c1 * 16 + srow) * K + scol;
    const u16* Bg0 = Bw + (size_t)(n0 + w * 16 + srow) * K + scol;

    const int lx = lhi ^ ((lcol >> 2) & 2);

    f32x4 acc[4][2] = {};

    GLD16(Ag0, &As[c0 * 512]);
    GLD16(Ag1, &As[c1 * 512]);
    GLD16(Bg0, &Bs[w * 512]);
    __syncthreads();

    int cur = 0;
    for (int k0 = 0; k0 < K; k0 += 32) {
        if (k0 + 32 < K) {
            GLD16(Ag0 + k0 + 32, &As[(cur ^ 1) * 4096 + c0 * 512]);
            GLD16(Ag1 + k0 + 32, &As[(cur ^ 1) * 4096 + c1 * 512]);
            GLD16(Bg0 + k0 + 32, &Bs[(cur ^ 1) * 2048 + w * 512]);
        }
        const int ca = cur * 4096, cb2 = cur * 2048;
        bf16x8 af[4], bfr[2];
        #pragma unroll
        for (int i = 0; i < 4; ++i)
            af[i] = *(const bf16x8*)&As[ca + (wm * 64 + i * 16 + lcol) * 32 + lx * 8];
        #pragma unroll
        for (int j = 0; j < 2; ++j)
            bfr[j] = *(const bf16x8*)&Bs[cb2 + (wn * 32 + j * 16 + lcol) * 32 + lx * 8];
        __builtin_amdgcn_s_setprio(1);
        #pragma unroll
        for (int i = 0; i < 4; ++i)
            #pragma unroll
            for (int j = 0; j < 2; ++j)
                acc[i][j] = mfma16x16(af[i], bfr[j], acc[i][j]);
        __builtin_amdgcn_s_setprio(0);
        __syncthreads();
        cur ^= 1;
    }

    #pragma unroll
    for (int i = 0; i < 4; ++i)
      #pragma unroll
      for (int j = 0; j < 2; ++j)
        #pragma unroll
        for (int r = 0; r < 4; ++r) {
            int m = m0 + wm * 64 + i * 16 + lhi * 4 + r;
            int n = n0 + wn * 32 + j * 16 + lcol;
            outf[(size_t)m * HD + n] = acc[i][j][r];
        }
}

// ---------------- flash attention: 4 waves x 32 q, LDS tile 64, split-KV x4 ----------------
// Grid 1024 = 32 bh x 8 qblk x 4 splits -> 4 blocks/CU (r7 core was 3/CU; attn is
// below the residency knee, so +1 block/CU buys TLP latency cover).
__global__ __launch_bounds__(256, 4) void k_attn(
    const u16* __restrict__ qb, const u16* __restrict__ kb,
    const u16* __restrict__ vt, u16* __restrict__ pO,
    float* __restrict__ pM, float* __restrict__ pL,
    const int* __restrict__ plp)
{
    __shared__ __align__(16) u16 Ks[64 * 128];   // [key][dh], chunk-swizzled
    __shared__ __align__(16) u16 Vs[128 * 64];   // [dh][key], chunk-swizzled

    const int past = *plp;                 // 1024
    const int tid = threadIdx.x, w = tid >> 6, lane = tid & 63;
    const int l31 = lane & 31, hi = lane >> 5;

    const int bid = blockIdx.x;            // 0..1023
    const int orig = (bid & 7) * 128 + (bid >> 3);   // XCD-bijective
    const int split = orig & 3;
    const int rest = orig >> 2;            // 0..255
    const int qblk = rest & 7;
    const int bh = rest >> 3;              // 0..31
    const int q0b = qblk * 128;
    const int q0 = q0b + w * 32;           // wave's q base
    const int q = q0 + l31;                // this lane's q row

    const u16* qx = qb + (size_t)bh * HS * HDH;
    const u16* kx = kb + (size_t)bh * HSF * HDH;
    const u16* vx = vt + (size_t)bh * HDH * HSF;

    bf16x8 qf[8];
    #pragma unroll
    for (int c = 0; c < 8; ++c)
        qf[c] = *(const bf16x8*)&qx[(size_t)q * HDH + c * 16 + hi * 8];

    const int krow0 = w * 16 + (lane >> 4);    // +4i
    const int kchunk = lane & 15;
    const int vrow0 = w * 32 + (lane >> 3);    // +8i
    const int vchunk = lane & 7;

    f32x16 o[4] = {};
    float mr = -3e38f, lr = 0.f;

    int nkt = (q0b + 128 + past + 63) >> 6;
    if (nkt > HSF / 64) nkt = HSF / 64;
    const int t0 = (split * nkt) >> 2;
    const int t1 = ((split + 1) * nkt) >> 2;

    for (int kt = t0; kt < t1; ++kt) {
        const int j0 = kt * 64;
        __syncthreads();
        #pragma unroll
        for (int i = 0; i < 4; ++i) {
            int rk = krow0 + 4 * i;
            GLD16(kx + (size_t)(j0 + rk) * HDH + ((kchunk ^ (rk & 7)) * 8),
                  Ks + w * 2048 + i * 512);
            int rv = vrow0 + 8 * i;
            GLD16(vx + (size_t)rv * HSF + j0 + ((vchunk ^ (rv & 7)) * 8),
                  Vs + w * 2048 + i * 512);
        }
        __syncthreads();

        if (j0 > q0 + 31 + past) continue;

        const char* ksb = (const char*)Ks;
        f32x16 sf0 = {}, sf1 = {};
        const int sw = l31 & 7;
        __builtin_amdgcn_s_setprio(1);
        #pragma unroll
        for (int c = 0; c < 8; ++c) {
            int ch = ((c * 2 + hi) ^ sw) * 16;
            bf16x8 ak0 = *(const bf16x8*)(ksb + l31 * 256 + ch);
            sf0 = mfma32x32(ak0, qf[c], sf0);
            bf16x8 ak1 = *(const bf16x8*)(ksb + (32 + l31) * 256 + ch);
            sf1 = mfma32x32(ak1, qf[c], sf1);
        }
        __builtin_amdgcn_s_setprio(0);

        if (j0 + 63 > q0 + past) {
            #pragma unroll
            for (int r = 0; r < 16; ++r) {
                int ko = (r & 3) + 8 * (r >> 2) + 4 * hi;
                if (j0 + ko > q + past)      sf0[r] = -3e38f;
                if (j0 + 32 + ko > q + past) sf1[r] = -3e38f;
            }
        }
        float pmax = -3e38f;
        #pragma unroll
        for (int r = 0; r < 16; ++r)
            pmax = fmaxf(pmax, fmaxf(sf0[r], sf1[r]));
        pmax = fmaxf(pmax, __shfl_xor(pmax, 32, 64));
        if (!__all((int)(pmax <= mr + 8.f))) {   // defer-max (T13)
            float mnew = fmaxf(mr, pmax);
            float alpha = exp2f(mr - mnew);
            mr = mnew;
            lr *= alpha;
            #pragma unroll
            for (int dt = 0; dt < 4; ++dt) o[dt] *= alpha;
        }
        float ps = 0.f;
        #pragma unroll
        for (int r = 0; r < 16; ++r) {
            sf0[r] = exp2f(sf0[r] - mr);
            sf1[r] = exp2f(sf1[r] - mr);
            ps += sf0[r] + sf1[r];
        }
        ps += __shfl_xor(ps, 32, 64);
        lr += ps;

        u32 wA[8], wB[8];
        #pragma unroll
        for (int g = 0; g < 4; ++g) {
            asm("v_cvt_pk_bf16_f32 %0, %1, %2" : "=v"(wA[2*g])   : "v"(sf0[4*g+0]), "v"(sf0[4*g+1]));
            asm("v_cvt_pk_bf16_f32 %0, %1, %2" : "=v"(wA[2*g+1]) : "v"(sf0[4*g+2]), "v"(sf0[4*g+3]));
            asm("v_cvt_pk_bf16_f32 %0, %1, %2" : "=v"(wB[2*g])   : "v"(sf1[4*g+0]), "v"(sf1[4*g+1]));
            asm("v_cvt_pk_bf16_f32 %0, %1, %2" : "=v"(wB[2*g+1]) : "v"(sf1[4*g+2]), "v"(sf1[4*g+3]));
        }
        pl32swap(wA[0], wA[2]); pl32swap(wA[1], wA[3]);
        pl32swap(wA[4], wA[6]); pl32swap(wA[5], wA[7]);
        pl32swap(wB[0], wB[2]); pl32swap(wB[1], wB[3]);
        pl32swap(wB[4], wB[6]); pl32swap(wB[5], wB[7]);
        union uf { u32 u[4]; bf16x8 v; };
        uf pf0, pf1, pf2, pf3;
        pf0.u[0]=wA[0]; pf0.u[1]=wA[1]; pf0.u[2]=wA[2]; pf0.u[3]=wA[3];
        pf1.u[0]=wA[4]; pf1.u[1]=wA[5]; pf1.u[2]=wA[6]; pf1.u[3]=wA[7];
        pf2.u[0]=wB[0]; pf2.u[1]=wB[1]; pf2.u[2]=wB[2]; pf2.u[3]=wB[3];
        pf3.u[0]=wB[4]; pf3.u[1]=wB[5]; pf3.u[2]=wB[6]; pf3.u[3]=wB[7];

        const char* vsb = (const char*)Vs;
        __builtin_amdgcn_s_setprio(1);
        #pragma unroll
        for (int dt = 0; dt < 4; ++dt) {
            int rb = (dt * 32 + l31) * 128;
            bf16x8 av0 = *(const bf16x8*)(vsb + rb + (((0 + hi) ^ sw) * 16));
            o[dt] = mfma32x32(av0, pf0.v, o[dt]);
            bf16x8 av1 = *(const bf16x8*)(vsb + rb + (((2 + hi) ^ sw) * 16));
            o[dt] = mfma32x32(av1, pf1.v, o[dt]);
            bf16x8 av2 = *(const bf16x8*)(vsb + rb + (((4 + hi) ^ sw) * 16));
            o[dt] = mfma32x32(av2, pf2.v, o[dt]);
            bf16x8 av3 = *(const bf16x8*)(vsb + rb + (((6 + hi) ^ sw) * 16));
            o[dt] = mfma32x32(av3, pf3.v, o[dt]);
        }
        __builtin_amdgcn_s_setprio(0);
    }

    const int qg = bh * HS + q;
    if (hi == 0) {
        pM[split * 32768 + qg] = mr;
        pL[split * 32768 + qg] = lr;
    }
    u16* prow = pO + ((size_t)split * 32768 + qg) * 128;
    #pragma unroll
    for (int dt = 0; dt < 4; ++dt)
        #pragma unroll
        for (int g = 0; g < 4; ++g) {
            ushort4 wv;
            wv.x = f2b(o[dt][4*g+0]);
            wv.y = f2b(o[dt][4*g+1]);
            wv.z = f2b(o[dt][4*g+2]);
            wv.w = f2b(o[dt][4*g+3]);
            *(ushort4*)(prow + dt * 32 + 8 * g + 4 * hi) = wv;
        }
}

// ---------------- combine the four KV-split partials ----------------
__global__ __launch_bounds__(256) void k_combine(
    const u16* __restrict__ pO, const float* __restrict__ pM,
    const float* __restrict__ pL, u16* __restrict__ ctx)
{
    int t = blockIdx.x * 256 + threadIdx.x;      // 0..1048575
    int qg = t >> 5;                             // bh*1024 + q
    int d4 = (t & 31) << 2;
    float m0 = pM[qg],         m1 = pM[32768 + qg];
    float m2 = pM[65536 + qg], m3 = pM[98304 + qg];
    float l0 = pL[qg],         l1 = pL[32768 + qg];
    float l2 = pL[65536 + qg], l3 = pL[98304 + qg];
    float M = fmaxf(fmaxf(m0, m1), fmaxf(m2, m3));
    float a0 = exp2f(m0 - M), a1 = exp2f(m1 - M);
    float a2 = exp2f(m2 - M), a3 = exp2f(m3 - M);
    float inv = 1.f / (a0 * l0 + a1 * l1 + a2 * l2 + a3 * l3);
    a0 *= inv; a1 *= inv; a2 *= inv; a3 *= inv;
    ushort4 v0 = *(const ushort4*)(pO + (size_t)qg * 128 + d4);
    ushort4 v1 = *(const ushort4*)(pO + ((size_t)32768 + qg) * 128 + d4);
    ushort4 v2 = *(const ushort4*)(pO + ((size_t)65536 + qg) * 128 + d4);
    ushort4 v3 = *(const ushort4*)(pO + ((size_t)98304 + qg) * 128 + d4);
    int bh = qg >> 10, qq = qg & 1023;
    int b = bh >> 4, hh = bh & 15;
    u16* crow = ctx + ((size_t)(b * HS + qq)) * HD + hh * HDH + d4;
    ushort4 wv;
    wv.x = f2b(a0 * b2f(v0.x) + a1 * b2f(v1.x) + a2 * b2f(v2.x) + a3 * b2f(v3.x));
    wv.y = f2b(a0 * b2f(v0.y) + a1 * b2f(v1.y) + a2 * b2f(v2.y) + a3 * b2f(v3.y));
    wv.z = f2b(a0 * b2f(v0.z) + a1 * b2f(v1.z) + a2 * b2f(v2.z) + a3 * b2f(v3.z));
    wv.w = f2b(a0 * b2f(v0.w) + a1 * b2f(v1.w) + a2 * b2f(v2.w) + a3 * b2f(v3.w));
    *(ushort4*)crow = wv;
}

// ---------------- launch ----------------
extern "C" void kernel_launch(void* const* d_in, const int* in_sizes, int n_in,
                              void* d_out, int out_size, void* d_ws, size_t ws_size,
                              hipStream_t stream) {
    const float* x   = (const float*)d_in[0];
    const float* kc  = (const float*)d_in[1];
    const float* vc  = (const float*)d_in[2];
    const float* qkv = (const float*)d_in[3];
    const float* wo  = (const float*)d_in[4];
    const int* plp   = (const int*)d_in[5];

    float* out = (float*)d_out;
    float* kf  = out + (size_t)HB * HS * HD;        // k_full
    float* vf  = kf + (size_t)HB * HH * HSF * HDH;  // v_full

    char* ws = (char*)d_ws;
    size_t o1 = (size_t)HM * HD * 2;
    size_t o2 = o1 + (size_t)HD3 * HD * 2;
    size_t o3 = o2 + (size_t)HD * HD * 2;
    size_t o4 = o3 + (size_t)HB * HH * HS * HDH * 2;
    size_t o5 = o4 + (size_t)HB * HH * HSF * HDH * 2;
    size_t o6 = o5 + (size_t)HB * HH * HSF * HDH * 2;
    u16* xb   = (u16*)(ws);
    u16* qkvb = (u16*)(ws + o1);
    u16* wob  = (u16*)(ws + o2);
    u16* qb   = (u16*)(ws + o3);
    u16* kb   = (u16*)(ws + o4);
    u16* vt   = (u16*)(ws + o5);
    u16* ctxb = (u16*)(ws + o6);
    // attention partials: pO (4 splits, 33.55MB) aliases xb+qkvb exactly (dead
    // after gemm_qkv); pM/pL (1MB) live in the `out` f32 section of d_out,
    // which is only written by gemm_out afterwards.
    u16* pO   = (u16*)ws;
    float* pM = out;                  // 4*32768 f32 = 0.5MB
    float* pL = out + 4 * 32768;      // 4*32768 f32 = 0.5MB  (<= 16.78MB section)

    k_prep<<<2048, 256, 0, stream>>>(x, xb, HM * HD / 4,
                                     qkv, qkvb, HD3 * HD / 4,
                                     wo, wob, HD * HD / 4,
                                     kc, vc, kf, vf, kb, vt);

    k_gemm_qkv<<<768, 256, 0, stream>>>(
        xb, qkvb, HD, qb, kf, vf, kb, vt);

    k_attn<<<1024, 256, 0, stream>>>(qb, kb, vt, pO, pM, pL, plp);
    k_combine<<<4096, 256, 0, stream>>>(pO, pM, pL, ctxb);

    k_gemm_out<<<512, 256, 0, stream>>>(ctxb, wob, HD, out);
}

// Round 19
// 195.965 us; speedup vs baseline: 1.1605x; 1.1605x over previous
//
#include <hip/hip_runtime.h>
#include <cstdint>

#define HB 2
#define HS 1024
#define HSF 2048
#define HH 16
#define HDH 128
#define HD 2048
#define HD3 6144
#define HM 2048  // HB*HS

typedef __attribute__((ext_vector_type(8))) short bf16x8;
typedef __attribute__((ext_vector_type(4))) float f32x4;
typedef __attribute__((ext_vector_type(16))) float f32x16;
typedef unsigned short u16;
typedef unsigned int u32;

__device__ __forceinline__ u16 f2b(float f) {
    union { float f; u32 u; } v; v.f = f;
    u32 u = v.u;
    return (u16)((u + 0x7FFFu + ((u >> 16) & 1u)) >> 16);
}
__device__ __forceinline__ float b2f(u16 h) {
    union { u32 u; float f; } v; v.u = ((u32)h) << 16; return v.f;
}

__device__ __forceinline__ f32x4 mfma16x16(bf16x8 a, bf16x8 b, f32x4 c) {
    return __builtin_amdgcn_mfma_f32_16x16x32_bf16(a, b, c, 0, 0, 0);
}
__device__ __forceinline__ f32x16 mfma32x32(bf16x8 a, bf16x8 b, f32x16 c) {
    return __builtin_amdgcn_mfma_f32_32x32x16_bf16(a, b, c, 0, 0, 0);
}
__device__ __forceinline__ void pl32swap(u32 &a, u32 &b) {
    asm volatile("v_permlane32_swap_b32 %0, %1" : "+v"(a), "+v"(b));
}

#define GLD16(gp, lp) __builtin_amdgcn_global_load_lds( \
    (__attribute__((address_space(1))) void*)(gp), \
    (__attribute__((address_space(3))) void*)(lp), 16, 0, 0)

// ---------------- fused streaming prep (r13-proven) ----------------
__global__ __launch_bounds__(256) void k_prep(
    const float* __restrict__ x,  u16* __restrict__ xb,  int n0,
    const float* __restrict__ qkv, u16* __restrict__ qkvb, int n1,
    const float* __restrict__ wo,  u16* __restrict__ wob, int n2,
    const float* __restrict__ kc, const float* __restrict__ vc,
    float* __restrict__ kf, float* __restrict__ vf,
    u16* __restrict__ kb, u16* __restrict__ vt)
{
    const int bid = blockIdx.x;
    const int tid = threadIdx.x;
    if (bid < 512) {
        __shared__ u16 Lt[128 * 66];      // [dh][s] — stride 66
        int bh = bid >> 4, st = (bid & 15) << 6;
        size_t cbase = (size_t)bh * (HS * HDH) + (size_t)st * HDH;
        size_t fbase = (size_t)bh * (HSF * HDH) + (size_t)st * HDH;
        #pragma unroll
        for (int i = 0; i < 8; ++i) {
            int ci = i * 256 + tid;
            float4 kv = ((const float4*)(kc + cbase))[ci];
            ((float4*)(kf + fbase))[ci] = kv;
            ushort4 k4;
            k4.x = f2b(kv.x); k4.y = f2b(kv.y); k4.z = f2b(kv.z); k4.w = f2b(kv.w);
            ((ushort4*)(kb + fbase))[ci] = k4;
        }
        #pragma unroll
        for (int i = 0; i < 8; ++i) {
            int ci = i * 256 + tid;
            int r = ci >> 5, c = ci & 31;
            float4 vv = ((const float4*)(vc + cbase))[ci];
            ((float4*)(vf + fbase))[ci] = vv;
            int dh = c * 4;
            Lt[(dh + 0) * 66 + r] = f2b(vv.x);
            Lt[(dh + 1) * 66 + r] = f2b(vv.y);
            Lt[(dh + 2) * 66 + r] = f2b(vv.z);
            Lt[(dh + 3) * 66 + r] = f2b(vv.w);
        }
        __syncthreads();
        u16* vtb = vt + (size_t)bh * (HDH * HSF) + st;
        #pragma unroll
        for (int i = 0; i < 4; ++i) {
            int ci = i * 256 + tid;
            int dh = ci >> 3, cs = (ci & 7) * 8;
            const u16* lr = &Lt[dh * 66 + cs];
            ushort4 lo, hi2;
            lo.x = lr[0]; lo.y = lr[1]; lo.z = lr[2]; lo.w = lr[3];
            hi2.x = lr[4]; hi2.y = lr[5]; hi2.z = lr[6]; hi2.w = lr[7];
            u16* dst = vtb + (size_t)dh * HSF + cs;
            *(ushort4*)dst = lo;
            *(ushort4*)(dst + 4) = hi2;
        }
    } else {
        int i = (bid - 512) * 256 + tid;
        const int st_ = ((int)gridDim.x - 512) * 256;
        const int nt = n0 + n1 + n2;
        for (; i < nt; i += st_) {
            const float* s; u16* d; int j = i;
            if (j < n0) { s = x; d = xb; }
            else if (j < n0 + n1) { j -= n0; s = qkv; d = qkvb; }
            else { j -= n0 + n1; s = wo; d = wob; }
            float4 v = ((const float4*)s)[j];
            ushort4 o;
            o.x = f2b(v.x); o.y = f2b(v.y); o.z = f2b(v.z); o.w = f2b(v.w);
            ((ushort4*)d)[j] = o;
        }
    }
}

// ---------------- QKV GEMM: 128x128 tile, BK=32, 2-phase dbuf (r17-proven) ----------------
// V-blocks (sec==2): vt emitted via LDS transpose (reusing the 32KB staging
// buffer post-loop) -> coalesced 16B stores instead of scalar u16 at 4KB stride.
__global__ __launch_bounds__(256, 2) void k_gemm_qkv(
    const u16* __restrict__ A, const u16* __restrict__ Bw, int K,
    u16* __restrict__ qb, float* __restrict__ kf, float* __restrict__ vf,
    u16* __restrict__ kb, u16* __restrict__ vt)
{
    __shared__ __align__(16) u16 SH[16384];   // As = SH[0..8191], Bs = SH[8192..]
    u16* As = SH;
    u16* Bs = SH + 8192;
    const int tid = threadIdx.x;
    const int w = tid >> 6, lane = tid & 63;
    const int wm = w >> 1, wn = w & 1;
    const int lcol = lane & 15, lhi = lane >> 4;

    const int nb = (int)gridDim.x, per = nb >> 3;
    const int bf = (int)blockIdx.x;
    const int t = (bf & 7) * per + (bf >> 3);
    const int m0 = (t & 15) * 128, n0 = (t >> 4) * 128;

    const int srow = lane >> 2;
    const int scol = ((lane & 3) ^ ((lane >> 4) & 2)) * 8;  // pre-swizzled source chunk
    const int c0 = w * 2, c1 = w * 2 + 1;
    const u16* Ag0 = A + (size_t)(m0 + c0 * 16 + srow) * K + scol;
    const u16* Ag1 = A + (size_t)(m0 + c1 * 16 + srow) * K + scol;
    const u16* Bg0 = Bw + (size_t)(n0 + c0 * 16 + srow) * K + scol;
    const u16* Bg1 = Bw + (size_t)(n0 + c1 * 16 + srow) * K + scol;

    const int lx = lhi ^ ((lcol >> 2) & 2);            // swizzled read chunk

    f32x4 acc[4][4] = {};

    GLD16(Ag0, &As[c0 * 512]);
    GLD16(Ag1, &As[c1 * 512]);
    GLD16(Bg0, &Bs[c0 * 512]);
    GLD16(Bg1, &Bs[c1 * 512]);
    __syncthreads();

    int cur = 0;
    for (int k0 = 0; k0 < K; k0 += 32) {
        if (k0 + 32 < K) {
            int nb_ = (cur ^ 1) * 4096;
            GLD16(Ag0 + k0 + 32, &As[nb_ + c0 * 512]);
            GLD16(Ag1 + k0 + 32, &As[nb_ + c1 * 512]);
            GLD16(Bg0 + k0 + 32, &Bs[nb_ + c0 * 512]);
            GLD16(Bg1 + k0 + 32, &Bs[nb_ + c1 * 512]);
        }
        const int cb = cur * 4096;
        bf16x8 af[4], bfr[4];
        #pragma unroll
        for (int i = 0; i < 4; ++i)
            af[i] = *(const bf16x8*)&As[cb + (wm * 64 + i * 16 + lcol) * 32 + lx * 8];
        #pragma unroll
        for (int i = 0; i < 4; ++i)
            bfr[i] = *(const bf16x8*)&Bs[cb + (wn * 64 + i * 16 + lcol) * 32 + lx * 8];
        __builtin_amdgcn_s_setprio(1);
        #pragma unroll
        for (int i = 0; i < 4; ++i)
            #pragma unroll
            for (int j = 0; j < 4; ++j)
                acc[i][j] = mfma16x16(af[i], bfr[j], acc[i][j]);
        __builtin_amdgcn_s_setprio(0);
        __syncthreads();
        cur ^= 1;
    }

    const int bsec = n0 >> 11;               // block-uniform section (0=Q,1=K,2=V)
    if (bsec == 2) {
        // ---- V block: vf scatter + LDS-transposed coalesced vt ----
        u16* T = SH;                         // 128x128 u16, XOR-swizzled columns
        #pragma unroll
        for (int i = 0; i < 4; ++i) {
          #pragma unroll
          for (int j = 0; j < 4; ++j) {
            #pragma unroll
            for (int r = 0; r < 4; ++r) {
                int sl = wm * 64 + i * 16 + lhi * 4 + r;     // local s (m)
                int dl = wn * 64 + j * 16 + lcol;            // local dh (n)
                int m = m0 + sl, n = n0 + dl;
                float v = acc[i][j][r];
                int b = m >> 10, s = m & 1023;
                int e = n & 2047;
                int h = e >> 7, dh = e & 127;
                int bh = b * HH + h;
                vf[((size_t)bh * HSF + HS + s) * HDH + dh] = v;
                T[dl * 128 + (sl ^ ((dl & 15) << 3))] = f2b(v);
            }
          }
        }
        __syncthreads();
        const int b2 = m0 >> 10, s0 = m0 & 1023;
        const int hh = (n0 & 2047) >> 7;
        const int bh2 = b2 * HH + hh;
        u16* vtb = vt + (size_t)(bh2 * HDH) * HSF + HS + s0;
        #pragma unroll
        for (int it = 0; it < 8; ++it) {
            int ci = it * 256 + tid;                 // 0..2047 chunks of 8
            int dl = ci >> 4, ch = ci & 15;
            const u16* lr = &T[dl * 128 + ((ch * 8) ^ ((dl & 15) << 3))];
            ushort4 lo = *(const ushort4*)lr;
            ushort4 hi2 = *(const ushort4*)(lr + 4);
            u16* dst = vtb + (size_t)dl * HSF + ch * 8;
            *(ushort4*)dst = lo;
            *(ushort4*)(dst + 4) = hi2;
        }
    } else {
        #pragma unroll
        for (int i = 0; i < 4; ++i) {
          #pragma unroll
          for (int j = 0; j < 4; ++j) {
            #pragma unroll
            for (int r = 0; r < 4; ++r) {
                int m = m0 + wm * 64 + i * 16 + lhi * 4 + r;
                int n = n0 + wn * 64 + j * 16 + lcol;
                float v = acc[i][j][r];
                int b = m >> 10, s = m & 1023;
                int e = n & 2047;
                int h = e >> 7, dh = e & 127;
                int bh = b * HH + h;
                if (bsec == 0) {
                    // pre-scale Q by 1/sqrt(dh) * log2(e) for exp2-domain softmax
                    qb[((size_t)bh * HS + s) * HDH + dh] = f2b(v * 0.12751742f);
                } else {
                    size_t idx = ((size_t)bh * HSF + HS + s) * HDH + dh;
                    kf[idx] = v; kb[idx] = f2b(v);
                }
            }
          }
        }
    }
}

// ---------------- output GEMM: 128x64 tile, BK=32, 2-phase dbuf (r14-proven) ----------------
__global__ __launch_bounds__(256, 4) void k_gemm_out(
    const u16* __restrict__ A, const u16* __restrict__ Bw, int K,
    float* __restrict__ outf)
{
    __shared__ __align__(16) u16 As[2 * 128 * 32];   // 16 KB
    __shared__ __align__(16) u16 Bs[2 * 64 * 32];    // 8 KB
    const int tid = threadIdx.x;
    const int w = tid >> 6, lane = tid & 63;
    const int wm = w >> 1, wn = w & 1;
    const int lcol = lane & 15, lhi = lane >> 4;

    const int nb = (int)gridDim.x, per = nb >> 3;
    const int bf = (int)blockIdx.x;
    const int t = (bf & 7) * per + (bf >> 3);
    const int m0 = (t & 15) * 128, n0 = (t >> 4) * 64;

    const int srow = lane >> 2;
    const int scol = ((lane & 3) ^ ((lane >> 4) & 2)) * 8;
    const int c0 = w * 2, c1 = w * 2 + 1;
    const u16* Ag0 = A + (size_t)(m0 + c0 * 16 + srow) * K + scol;
    const u16* Ag1 = A + (size_t)(m0 + c1 * 16 + srow) * K + scol;
    const u16* Bg0 = Bw + (size_t)(n0 + w * 16 + srow) * K + scol;

    const int lx = lhi ^ ((lcol >> 2) & 2);

    f32x4 acc[4][2] = {};

    GLD16(Ag0, &As[c0 * 512]);
    GLD16(Ag1, &As[c1 * 512]);
    GLD16(Bg0, &Bs[w * 512]);
    __syncthreads();

    int cur = 0;
    for (int k0 = 0; k0 < K; k0 += 32) {
        if (k0 + 32 < K) {
            GLD16(Ag0 + k0 + 32, &As[(cur ^ 1) * 4096 + c0 * 512]);
            GLD16(Ag1 + k0 + 32, &As[(cur ^ 1) * 4096 + c1 * 512]);
            GLD16(Bg0 + k0 + 32, &Bs[(cur ^ 1) * 2048 + w * 512]);
        }
        const int ca = cur * 4096, cb2 = cur * 2048;
        bf16x8 af[4], bfr[2];
        #pragma unroll
        for (int i = 0; i < 4; ++i)
            af[i] = *(const bf16x8*)&As[ca + (wm * 64 + i * 16 + lcol) * 32 + lx * 8];
        #pragma unroll
        for (int j = 0; j < 2; ++j)
            bfr[j] = *(const bf16x8*)&Bs[cb2 + (wn * 32 + j * 16 + lcol) * 32 + lx * 8];
        __builtin_amdgcn_s_setprio(1);
        #pragma unroll
        for (int i = 0; i < 4; ++i)
            #pragma unroll
            for (int j = 0; j < 2; ++j)
                acc[i][j] = mfma16x16(af[i], bfr[j], acc[i][j]);
        __builtin_amdgcn_s_setprio(0);
        __syncthreads();
        cur ^= 1;
    }

    #pragma unroll
    for (int i = 0; i < 4; ++i)
      #pragma unroll
      for (int j = 0; j < 2; ++j)
        #pragma unroll
        for (int r = 0; r < 4; ++r) {
            int m = m0 + wm * 64 + i * 16 + lhi * 4 + r;
            int n = n0 + wn * 32 + j * 16 + lcol;
            outf[(size_t)m * HD + n] = acc[i][j][r];
        }
}

// ---------------- flash attention: 4 waves x 32 q, LDS tile 64, split-KV x3 ----------------
__global__ __launch_bounds__(256, 3) void k_attn(
    const u16* __restrict__ qb, const u16* __restrict__ kb,
    const u16* __restrict__ vt, u16* __restrict__ pO,
    float* __restrict__ pM, float* __restrict__ pL,
    const int* __restrict__ plp)
{
    __shared__ __align__(16) u16 Ks[64 * 128];   // [key][dh], chunk-swizzled
    __shared__ __align__(16) u16 Vs[128 * 64];   // [dh][key], chunk-swizzled

    const int past = *plp;                 // 1024
    const int tid = threadIdx.x, w = tid >> 6, lane = tid & 63;
    const int l31 = lane & 31, hi = lane >> 5;

    const int bid = blockIdx.x;            // 0..767
    const int orig = (bid & 7) * 96 + (bid >> 3);
    const int split = orig % 3;
    const int rest = orig / 3;             // 0..255
    const int qblk = rest & 7;
    const int bh = rest >> 3;              // 0..31
    const int q0b = qblk * 128;
    const int q0 = q0b + w * 32;           // wave's q base
    const int q = q0 + l31;                // this lane's q row

    const u16* qx = qb + (size_t)bh * HS * HDH;
    const u16* kx = kb + (size_t)bh * HSF * HDH;
    const u16* vx = vt + (size_t)bh * HDH * HSF;

    bf16x8 qf[8];
    #pragma unroll
    for (int c = 0; c < 8; ++c)
        qf[c] = *(const bf16x8*)&qx[(size_t)q * HDH + c * 16 + hi * 8];

    const int krow0 = w * 16 + (lane >> 4);    // +4i
    const int kchunk = lane & 15;
    const int vrow0 = w * 32 + (lane >> 3);    // +8i
    const int vchunk = lane & 7;

    f32x16 o[4] = {};
    float mr = -3e38f, lr = 0.f;

    int nkt = (q0b + 128 + past + 63) >> 6;
    if (nkt > HSF / 64) nkt = HSF / 64;
    const int t0 = (split * nkt) / 3;
    const int t1 = ((split + 1) * nkt) / 3;

    for (int kt = t0; kt < t1; ++kt) {
        const int j0 = kt * 64;
        __syncthreads();
        #pragma unroll
        for (int i = 0; i < 4; ++i) {
            int rk = krow0 + 4 * i;
            GLD16(kx + (size_t)(j0 + rk) * HDH + ((kchunk ^ (rk & 7)) * 8),
                  Ks + w * 2048 + i * 512);
            int rv = vrow0 + 8 * i;
            GLD16(vx + (size_t)rv * HSF + j0 + ((vchunk ^ (rv & 7)) * 8),
                  Vs + w * 2048 + i * 512);
        }
        __syncthreads();

        if (j0 > q0 + 31 + past) continue;

        const char* ksb = (const char*)Ks;
        f32x16 sf0 = {}, sf1 = {};
        const int sw = l31 & 7;
        __builtin_amdgcn_s_setprio(1);
        #pragma unroll
        for (int c = 0; c < 8; ++c) {
            int ch = ((c * 2 + hi) ^ sw) * 16;
            bf16x8 ak0 = *(const bf16x8*)(ksb + l31 * 256 + ch);
            sf0 = mfma32x32(ak0, qf[c], sf0);
            bf16x8 ak1 = *(const bf16x8*)(ksb + (32 + l31) * 256 + ch);
            sf1 = mfma32x32(ak1, qf[c], sf1);
        }
        __builtin_amdgcn_s_setprio(0);

        if (j0 + 63 > q0 + past) {
            #pragma unroll
            for (int r = 0; r < 16; ++r) {
                int ko = (r & 3) + 8 * (r >> 2) + 4 * hi;
                if (j0 + ko > q + past)      sf0[r] = -3e38f;
                if (j0 + 32 + ko > q + past) sf1[r] = -3e38f;
            }
        }
        float pmax = -3e38f;
        #pragma unroll
        for (int r = 0; r < 16; ++r)
            pmax = fmaxf(pmax, fmaxf(sf0[r], sf1[r]));
        pmax = fmaxf(pmax, __shfl_xor(pmax, 32, 64));
        if (!__all((int)(pmax <= mr + 8.f))) {   // defer-max (T13)
            float mnew = fmaxf(mr, pmax);
            float alpha = exp2f(mr - mnew);
            mr = mnew;
            lr *= alpha;
            #pragma unroll
            for (int dt = 0; dt < 4; ++dt) o[dt] *= alpha;
        }
        float ps = 0.f;
        #pragma unroll
        for (int r = 0; r < 16; ++r) {
            sf0[r] = exp2f(sf0[r] - mr);
            sf1[r] = exp2f(sf1[r] - mr);
            ps += sf0[r] + sf1[r];
        }
        ps += __shfl_xor(ps, 32, 64);
        lr += ps;

        u32 wA[8], wB[8];
        #pragma unroll
        for (int g = 0; g < 4; ++g) {
            asm("v_cvt_pk_bf16_f32 %0, %1, %2" : "=v"(wA[2*g])   : "v"(sf0[4*g+0]), "v"(sf0[4*g+1]));
            asm("v_cvt_pk_bf16_f32 %0, %1, %2" : "=v"(wA[2*g+1]) : "v"(sf0[4*g+2]), "v"(sf0[4*g+3]));
            asm("v_cvt_pk_bf16_f32 %0, %1, %2" : "=v"(wB[2*g])   : "v"(sf1[4*g+0]), "v"(sf1[4*g+1]));
            asm("v_cvt_pk_bf16_f32 %0, %1, %2" : "=v"(wB[2*g+1]) : "v"(sf1[4*g+2]), "v"(sf1[4*g+3]));
        }
        pl32swap(wA[0], wA[2]); pl32swap(wA[1], wA[3]);
        pl32swap(wA[4], wA[6]); pl32swap(wA[5], wA[7]);
        pl32swap(wB[0], wB[2]); pl32swap(wB[1], wB[3]);
        pl32swap(wB[4], wB[6]); pl32swap(wB[5], wB[7]);
        union uf { u32 u[4]; bf16x8 v; };
        uf pf0, pf1, pf2, pf3;
        pf0.u[0]=wA[0]; pf0.u[1]=wA[1]; pf0.u[2]=wA[2]; pf0.u[3]=wA[3];
        pf1.u[0]=wA[4]; pf1.u[1]=wA[5]; pf1.u[2]=wA[6]; pf1.u[3]=wA[7];
        pf2.u[0]=wB[0]; pf2.u[1]=wB[1]; pf2.u[2]=wB[2]; pf2.u[3]=wB[3];
        pf3.u[0]=wB[4]; pf3.u[1]=wB[5]; pf3.u[2]=wB[6]; pf3.u[3]=wB[7];

        const char* vsb = (const char*)Vs;
        __builtin_amdgcn_s_setprio(1);
        #pragma unroll
        for (int dt = 0; dt < 4; ++dt) {
            int rb = (dt * 32 + l31) * 128;
            bf16x8 av0 = *(const bf16x8*)(vsb + rb + (((0 + hi) ^ sw) * 16));
            o[dt] = mfma32x32(av0, pf0.v, o[dt]);
            bf16x8 av1 = *(const bf16x8*)(vsb + rb + (((2 + hi) ^ sw) * 16));
            o[dt] = mfma32x32(av1, pf1.v, o[dt]);
            bf16x8 av2 = *(const bf16x8*)(vsb + rb + (((4 + hi) ^ sw) * 16));
            o[dt] = mfma32x32(av2, pf2.v, o[dt]);
            bf16x8 av3 = *(const bf16x8*)(vsb + rb + (((6 + hi) ^ sw) * 16));
            o[dt] = mfma32x32(av3, pf3.v, o[dt]);
        }
        __builtin_amdgcn_s_setprio(0);
    }

    const int qg = bh * HS + q;
    if (hi == 0) {
        pM[split * 32768 + qg] = mr;
        pL[split * 32768 + qg] = lr;
    }
    u16* prow = pO + ((size_t)split * 32768 + qg) * 128;
    #pragma unroll
    for (int dt = 0; dt < 4; ++dt)
        #pragma unroll
        for (int g = 0; g < 4; ++g) {
            ushort4 wv;
            wv.x = f2b(o[dt][4*g+0]);
            wv.y = f2b(o[dt][4*g+1]);
            wv.z = f2b(o[dt][4*g+2]);
            wv.w = f2b(o[dt][4*g+3]);
            *(ushort4*)(prow + dt * 32 + 8 * g + 4 * hi) = wv;
        }
}

// ---------------- combine the three KV-split partials ----------------
__global__ __launch_bounds__(256) void k_combine(
    const u16* __restrict__ pO, const float* __restrict__ pM,
    const float* __restrict__ pL, u16* __restrict__ ctx)
{
    int t = blockIdx.x * 256 + threadIdx.x;      // 0..1048575
    int qg = t >> 5;                             // bh*1024 + q
    int d4 = (t & 31) << 2;
    float m0 = pM[qg], m1 = pM[32768 + qg], m2 = pM[65536 + qg];
    float l0 = pL[qg], l1 = pL[32768 + qg], l2 = pL[65536 + qg];
    float M = fmaxf(fmaxf(m0, m1), m2);
    float a0 = exp2f(m0 - M), a1 = exp2f(m1 - M), a2 = exp2f(m2 - M);
    float inv = 1.f / (a0 * l0 + a1 * l1 + a2 * l2);
    a0 *= inv; a1 *= inv; a2 *= inv;
    ushort4 v0 = *(const ushort4*)(pO + (size_t)qg * 128 + d4);
    ushort4 v1 = *(const ushort4*)(pO + ((size_t)32768 + qg) * 128 + d4);
    ushort4 v2 = *(const ushort4*)(pO + ((size_t)65536 + qg) * 128 + d4);
    int bh = qg >> 10, qq = qg & 1023;
    int b = bh >> 4, hh = bh & 15;
    u16* crow = ctx + ((size_t)(b * HS + qq)) * HD + hh * HDH + d4;
    ushort4 wv;
    wv.x = f2b(a0 * b2f(v0.x) + a1 * b2f(v1.x) + a2 * b2f(v2.x));
    wv.y = f2b(a0 * b2f(v0.y) + a1 * b2f(v1.y) + a2 * b2f(v2.y));
    wv.z = f2b(a0 * b2f(v0.z) + a1 * b2f(v1.z) + a2 * b2f(v2.z));
    wv.w = f2b(a0 * b2f(v0.w) + a1 * b2f(v1.w) + a2 * b2f(v2.w));
    *(ushort4*)crow = wv;
}

// ---------------- launch ----------------
extern "C" void kernel_launch(void* const* d_in, const int* in_sizes, int n_in,
                              void* d_out, int out_size, void* d_ws, size_t ws_size,
                              hipStream_t stream) {
    const float* x   = (const float*)d_in[0];
    const float* kc  = (const float*)d_in[1];
    const float* vc  = (const float*)d_in[2];
    const float* qkv = (const float*)d_in[3];
    const float* wo  = (const float*)d_in[4];
    const int* plp   = (const int*)d_in[5];

    float* out = (float*)d_out;
    float* kf  = out + (size_t)HB * HS * HD;        // k_full
    float* vf  = kf + (size_t)HB * HH * HSF * HDH;  // v_full

    char* ws = (char*)d_ws;
    size_t o1 = (size_t)HM * HD * 2;
    size_t o2 = o1 + (size_t)HD3 * HD * 2;
    size_t o3 = o2 + (size_t)HD * HD * 2;
    size_t o4 = o3 + (size_t)HB * HH * HS * HDH * 2;
    size_t o5 = o4 + (size_t)HB * HH * HSF * HDH * 2;
    size_t o6 = o5 + (size_t)HB * HH * HSF * HDH * 2;
    u16* xb   = (u16*)(ws);
    u16* qkvb = (u16*)(ws + o1);
    u16* wob  = (u16*)(ws + o2);
    u16* qb   = (u16*)(ws + o3);
    u16* kb   = (u16*)(ws + o4);
    u16* vt   = (u16*)(ws + o5);
    u16* ctxb = (u16*)(ws + o6);
    // attention partials alias xb+qkvb (dead after gemm_qkv): 25.95MB <= 33.55MB
    u16* pO   = (u16*)ws;                                  // 3*32768*128 bf16 = 25.2MB
    float* pM = (float*)(ws + (size_t)3 * 32768 * 128 * 2);        // 3*32768 f32
    float* pL = (float*)(ws + (size_t)3 * 32768 * 128 * 2 + 393216);

    k_prep<<<2048, 256, 0, stream>>>(x, xb, HM * HD / 4,
                                     qkv, qkvb, HD3 * HD / 4,
                                     wo, wob, HD * HD / 4,
                                     kc, vc, kf, vf, kb, vt);

    k_gemm_qkv<<<768, 256, 0, stream>>>(
        xb, qkvb, HD, qb, kf, vf, kb, vt);

    k_attn<<<768, 256, 0, stream>>>(qb, kb, vt, pO, pM, pL, plp);
    k_combine<<<4096, 256, 0, stream>>>(pO, pM, pL, ctxb);

    k_gemm_out<<<512, 256, 0, stream>>>(ctxb, wob, HD, out);
}

// Round 20
// 193.745 us; speedup vs baseline: 1.1738x; 1.0115x over previous
//
#include <hip/hip_runtime.h>
#include <cstdint>

#define HB 2
#define HS 1024
#define HSF 2048
#define HH 16
#define HDH 128
#define HD 2048
#define HD3 6144
#define HM 2048  // HB*HS

typedef __attribute__((ext_vector_type(8))) short bf16x8;
typedef __attribute__((ext_vector_type(4))) float f32x4;
typedef __attribute__((ext_vector_type(16))) float f32x16;
typedef unsigned short u16;
typedef unsigned int u32;

__device__ __forceinline__ u16 f2b(float f) {
    union { float f; u32 u; } v; v.f = f;
    u32 u = v.u;
    return (u16)((u + 0x7FFFu + ((u >> 16) & 1u)) >> 16);
}
__device__ __forceinline__ float b2f(u16 h) {
    union { u32 u; float f; } v; v.u = ((u32)h) << 16; return v.f;
}

__device__ __forceinline__ f32x4 mfma16x16(bf16x8 a, bf16x8 b, f32x4 c) {
    return __builtin_amdgcn_mfma_f32_16x16x32_bf16(a, b, c, 0, 0, 0);
}
__device__ __forceinline__ f32x16 mfma32x32(bf16x8 a, bf16x8 b, f32x16 c) {
    return __builtin_amdgcn_mfma_f32_32x32x16_bf16(a, b, c, 0, 0, 0);
}
__device__ __forceinline__ void pl32swap(u32 &a, u32 &b) {
    asm volatile("v_permlane32_swap_b32 %0, %1" : "+v"(a), "+v"(b));
}

#define GLD16(gp, lp) __builtin_amdgcn_global_load_lds( \
    (__attribute__((address_space(1))) void*)(gp), \
    (__attribute__((address_space(3))) void*)(lp), 16, 0, 0)

// ---------------- fused streaming prep (r13-proven) ----------------
__global__ __launch_bounds__(256) void k_prep(
    const float* __restrict__ x,  u16* __restrict__ xb,  int n0,
    const float* __restrict__ qkv, u16* __restrict__ qkvb, int n1,
    const float* __restrict__ wo,  u16* __restrict__ wob, int n2,
    const float* __restrict__ kc, const float* __restrict__ vc,
    float* __restrict__ kf, float* __restrict__ vf,
    u16* __restrict__ kb, u16* __restrict__ vt)
{
    const int bid = blockIdx.x;
    const int tid = threadIdx.x;
    if (bid < 512) {
        __shared__ u16 Lt[128 * 66];      // [dh][s] — stride 66
        int bh = bid >> 4, st = (bid & 15) << 6;
        size_t cbase = (size_t)bh * (HS * HDH) + (size_t)st * HDH;
        size_t fbase = (size_t)bh * (HSF * HDH) + (size_t)st * HDH;
        #pragma unroll
        for (int i = 0; i < 8; ++i) {
            int ci = i * 256 + tid;
            float4 kv = ((const float4*)(kc + cbase))[ci];
            ((float4*)(kf + fbase))[ci] = kv;
            ushort4 k4;
            k4.x = f2b(kv.x); k4.y = f2b(kv.y); k4.z = f2b(kv.z); k4.w = f2b(kv.w);
            ((ushort4*)(kb + fbase))[ci] = k4;
        }
        #pragma unroll
        for (int i = 0; i < 8; ++i) {
            int ci = i * 256 + tid;
            int r = ci >> 5, c = ci & 31;
            float4 vv = ((const float4*)(vc + cbase))[ci];
            ((float4*)(vf + fbase))[ci] = vv;
            int dh = c * 4;
            Lt[(dh + 0) * 66 + r] = f2b(vv.x);
            Lt[(dh + 1) * 66 + r] = f2b(vv.y);
            Lt[(dh + 2) * 66 + r] = f2b(vv.z);
            Lt[(dh + 3) * 66 + r] = f2b(vv.w);
        }
        __syncthreads();
        u16* vtb = vt + (size_t)bh * (HDH * HSF) + st;
        #pragma unroll
        for (int i = 0; i < 4; ++i) {
            int ci = i * 256 + tid;
            int dh = ci >> 3, cs = (ci & 7) * 8;
            const u16* lr = &Lt[dh * 66 + cs];
            ushort4 lo, hi2;
            lo.x = lr[0]; lo.y = lr[1]; lo.z = lr[2]; lo.w = lr[3];
            hi2.x = lr[4]; hi2.y = lr[5]; hi2.z = lr[6]; hi2.w = lr[7];
            u16* dst = vtb + (size_t)dh * HSF + cs;
            *(ushort4*)dst = lo;
            *(ushort4*)(dst + 4) = hi2;
        }
    } else {
        int i = (bid - 512) * 256 + tid;
        const int st_ = ((int)gridDim.x - 512) * 256;
        const int nt = n0 + n1 + n2;
        for (; i < nt; i += st_) {
            const float* s; u16* d; int j = i;
            if (j < n0) { s = x; d = xb; }
            else if (j < n0 + n1) { j -= n0; s = qkv; d = qkvb; }
            else { j -= n0 + n1; s = wo; d = wob; }
            float4 v = ((const float4*)s)[j];
            ushort4 o;
            o.x = f2b(v.x); o.y = f2b(v.y); o.z = f2b(v.z); o.w = f2b(v.w);
            ((ushort4*)d)[j] = o;
        }
    }
}

// ---------------- QKV GEMM: 256x256 tile, BK=64, 2-phase dbuf ----------------
// 8 waves (2x4), LDS 128KB (2 buf x {A[256][64] + B[256][64]}). Stage-all 8
// GLDs at top of tile, ~700cy of compute (64 MFMA + 24 ds_read per wave)
// covers the ~600cy load latency -> the __syncthreads drain lands on
// completed loads (vs 128x128's 200cy window exposing ~500cy every iter).
// Swizzle: stored chunk c of row r holds global chunk c^(r&7) (r12-proven).
__global__ __launch_bounds__(512, 1) void k_gemm_qkv(
    const u16* __restrict__ A, const u16* __restrict__ Bw, int K,
    u16* __restrict__ qb, float* __restrict__ kf, float* __restrict__ vf,
    u16* __restrict__ kb, u16* __restrict__ vt)
{
    __shared__ __align__(16) u16 SH[65536];   // 128 KB
    const int tid = threadIdx.x;
    const int w = tid >> 6, lane = tid & 63;
    const int wr = w >> 2, wc = w & 3;
    const int lcol = lane & 15, lhi = lane >> 4;
    const int NT = 32;                        // K / 64

    // XCD-bijective: 24 consecutive tiles per XCD (A 8MB + 3MB B panel L2-fit)
    const int bf = (int)blockIdx.x;           // 0..191
    const int t = (bf & 7) * 24 + (bf >> 3);
    const int m0 = (t & 7) * 256, n0 = (t >> 3) * 256;

    // staging geometry: ci = L*512 + tid; row = ci>>3, chunk = ci&7 (8x8 u16 = 64k)
    const int srow = tid >> 3;                // row within 64-row L-slab
    const int schunk = tid & 7;

    auto STAGE = [&](int buf, int kt) {
        #pragma unroll
        for (int L = 0; L < 4; ++L) {
            int row = L * 64 + srow;
            int cs = (schunk ^ (row & 7)) * 8;
            GLD16(A + (size_t)(m0 + row) * K + kt * 64 + cs,
                  &SH[buf * 32768 + L * 4096 + w * 512]);
        }
        #pragma unroll
        for (int L = 0; L < 4; ++L) {
            int row = L * 64 + srow;
            int cs = (schunk ^ (row & 7)) * 8;
            GLD16(Bw + (size_t)(n0 + row) * K + kt * 64 + cs,
                  &SH[buf * 32768 + 16384 + L * 4096 + w * 512]);
        }
    };

    f32x4 acc[8][4] = {};

    STAGE(0, 0);
    __syncthreads();

    int cur = 0;
    for (int kt = 0; kt < NT; ++kt) {
        if (kt + 1 < NT) STAGE(cur ^ 1, kt + 1);
        const int ab = cur * 32768, bb = cur * 32768 + 16384;
        #pragma unroll
        for (int kk = 0; kk < 2; ++kk) {
            bf16x8 af[8], bfr[4];
            #pragma unroll
            for (int i = 0; i < 8; ++i) {
                int r = wr * 128 + i * 16 + lcol;
                int ch = (kk * 4 + lhi) ^ (r & 7);
                af[i] = *(const bf16x8*)&SH[ab + r * 64 + ch * 8];
            }
            #pragma unroll
            for (int j = 0; j < 4; ++j) {
                int r = wc * 64 + j * 16 + lcol;
                int ch = (kk * 4 + lhi) ^ (r & 7);
                bfr[j] = *(const bf16x8*)&SH[bb + r * 64 + ch * 8];
            }
            __builtin_amdgcn_s_setprio(1);
            #pragma unroll
            for (int i = 0; i < 8; ++i)
                #pragma unroll
                for (int j = 0; j < 4; ++j)
                    acc[i][j] = mfma16x16(af[i], bfr[j], acc[i][j]);
            __builtin_amdgcn_s_setprio(0);
        }
        __syncthreads();
        cur ^= 1;
    }

    const int bsec = n0 >> 11;               // block-uniform section (0=Q,1=K,2=V)
    if (bsec == 2) {
        // ---- V block: vf scatter + LDS-transposed coalesced vt (256-wide) ----
        u16* T = SH;                         // [256 dh][256 s], granule-XOR swizzled
        #pragma unroll
        for (int i = 0; i < 8; ++i) {
          #pragma unroll
          for (int j = 0; j < 4; ++j) {
            #pragma unroll
            for (int r = 0; r < 4; ++r) {
                int sl = wr * 128 + i * 16 + lhi * 4 + r;     // local s
                int dl = wc * 64 + j * 16 + lcol;             // local dh (2 heads)
                int m = m0 + sl, n = n0 + dl;
                float v = acc[i][j][r];
                int b = m >> 10, s = m & 1023;
                int e = n & 2047;
                int h = e >> 7, dh = e & 127;
                int bh = b * HH + h;
                vf[((size_t)bh * HSF + HS + s) * HDH + dh] = v;
                T[dl * 256 + (sl ^ ((dl & 31) << 3))] = f2b(v);
            }
          }
        }
        __syncthreads();
        const int b2 = m0 >> 10, s0 = m0 & 1023;
        #pragma unroll
        for (int it = 0; it < 16; ++it) {
            int ci = it * 512 + tid;                 // 0..8191 granules of 8 u16
            int dl = ci >> 5, cs = (ci & 31) * 8;
            const u16* lr = &T[dl * 256 + (cs ^ ((dl & 31) << 3))];
            ushort4 lo = *(const ushort4*)lr;
            ushort4 hi2 = *(const ushort4*)(lr + 4);
            int e = (n0 + dl) & 2047;
            int hh = e >> 7, dh = e & 127;
            u16* dst = vt + ((size_t)(b2 * HH + hh) * HDH + dh) * HSF + HS + s0 + cs;
            *(ushort4*)dst = lo;
            *(ushort4*)(dst + 4) = hi2;
        }
    } else {
        #pragma unroll
        for (int i = 0; i < 8; ++i) {
          #pragma unroll
          for (int j = 0; j < 4; ++j) {
            #pragma unroll
            for (int r = 0; r < 4; ++r) {
                int m = m0 + wr * 128 + i * 16 + lhi * 4 + r;
                int n = n0 + wc * 64 + j * 16 + lcol;
                float v = acc[i][j][r];
                int b = m >> 10, s = m & 1023;
                int e = n & 2047;
                int h = e >> 7, dh = e & 127;
                int bh = b * HH + h;
                if (bsec == 0) {
                    // pre-scale Q by 1/sqrt(dh) * log2(e) for exp2-domain softmax
                    qb[((size_t)bh * HS + s) * HDH + dh] = f2b(v * 0.12751742f);
                } else {
                    size_t idx = ((size_t)bh * HSF + HS + s) * HDH + dh;
                    kf[idx] = v; kb[idx] = f2b(v);
                }
            }
          }
        }
    }
}

// ---------------- output GEMM: 128x64 tile, BK=32, 2-phase dbuf (r14-proven) ----------------
__global__ __launch_bounds__(256, 4) void k_gemm_out(
    const u16* __restrict__ A, const u16* __restrict__ Bw, int K,
    float* __restrict__ outf)
{
    __shared__ __align__(16) u16 As[2 * 128 * 32];   // 16 KB
    __shared__ __align__(16) u16 Bs[2 * 64 * 32];    // 8 KB
    const int tid = threadIdx.x;
    const int w = tid >> 6, lane = tid & 63;
    const int wm = w >> 1, wn = w & 1;
    const int lcol = lane & 15, lhi = lane >> 4;

    const int nb = (int)gridDim.x, per = nb >> 3;
    const int bf = (int)blockIdx.x;
    const int t = (bf & 7) * per + (bf >> 3);
    const int m0 = (t & 15) * 128, n0 = (t >> 4) * 64;

    const int srow = lane >> 2;
    const int scol = ((lane & 3) ^ ((lane >> 4) & 2)) * 8;
    const int c0 = w * 2, c1 = w * 2 + 1;
    const u16* Ag0 = A + (size_t)(m0 + c0 * 16 + srow) * K + scol;
    const u16* Ag1 = A + (size_t)(m0 + c1 * 16 + srow) * K + scol;
    const u16* Bg0 = Bw + (size_t)(n0 + w * 16 + srow) * K + scol;

    const int lx = lhi ^ ((lcol >> 2) & 2);

    f32x4 acc[4][2] = {};

    GLD16(Ag0, &As[c0 * 512]);
    GLD16(Ag1, &As[c1 * 512]);
    GLD16(Bg0, &Bs[w * 512]);
    __syncthreads();

    int cur = 0;
    for (int k0 = 0; k0 < K; k0 += 32) {
        if (k0 + 32 < K) {
            GLD16(Ag0 + k0 + 32, &As[(cur ^ 1) * 4096 + c0 * 512]);
            GLD16(Ag1 + k0 + 32, &As[(cur ^ 1) * 4096 + c1 * 512]);
            GLD16(Bg0 + k0 + 32, &Bs[(cur ^ 1) * 2048 + w * 512]);
        }
        const int ca = cur * 4096, cb2 = cur * 2048;
        bf16x8 af[4], bfr[2];
        #pragma unroll
        for (int i = 0; i < 4; ++i)
            af[i] = *(const bf16x8*)&As[ca + (wm * 64 + i * 16 + lcol) * 32 + lx * 8];
        #pragma unroll
        for (int j = 0; j < 2; ++j)
            bfr[j] = *(const bf16x8*)&Bs[cb2 + (wn * 32 + j * 16 + lcol) * 32 + lx * 8];
        __builtin_amdgcn_s_setprio(1);
        #pragma unroll
        for (int i = 0; i < 4; ++i)
            #pragma unroll
            for (int j = 0; j < 2; ++j)
                acc[i][j] = mfma16x16(af[i], bfr[j], acc[i][j]);
        __builtin_amdgcn_s_setprio(0);
        __syncthreads();
        cur ^= 1;
    }

    #pragma unroll
    for (int i = 0; i < 4; ++i)
      #pragma unroll
      for (int j = 0; j < 2; ++j)
        #pragma unroll
        for (int r = 0; r < 4; ++r) {
            int m = m0 + wm * 64 + i * 16 + lhi * 4 + r;
            int n = n0 + wn * 32 + j * 16 + lcol;
            outf[(size_t)m * HD + n] = acc[i][j][r];
        }
}

// ---------------- flash attention: 4 waves x 32 q, LDS tile 64, split-KV x3 ----------------
__global__ __launch_bounds__(256, 3) void k_attn(
    const u16* __restrict__ qb, const u16* __restrict__ kb,
    const u16* __restrict__ vt, u16* __restrict__ pO,
    float* __restrict__ pM, float* __restrict__ pL,
    const int* __restrict__ plp)
{
    __shared__ __align__(16) u16 Ks[64 * 128];   // [key][dh], chunk-swizzled
    __shared__ __align__(16) u16 Vs[128 * 64];   // [dh][key], chunk-swizzled

    const int past = *plp;                 // 1024
    const int tid = threadIdx.x, w = tid >> 6, lane = tid & 63;
    const int l31 = lane & 31, hi = lane >> 5;

    const int bid = blockIdx.x;            // 0..767
    const int orig = (bid & 7) * 96 + (bid >> 3);
    const int split = orig % 3;
    const int rest = orig / 3;             // 0..255
    const int qblk = rest & 7;
    const int bh = rest >> 3;              // 0..31
    const int q0b = qblk * 128;
    const int q0 = q0b + w * 32;           // wave's q base
    const int q = q0 + l31;                // this lane's q row

    const u16* qx = qb + (size_t)bh * HS * HDH;
    const u16* kx = kb + (size_t)bh * HSF * HDH;
    const u16* vx = vt + (size_t)bh * HDH * HSF;

    bf16x8 qf[8];
    #pragma unroll
    for (int c = 0; c < 8; ++c)
        qf[c] = *(const bf16x8*)&qx[(size_t)q * HDH + c * 16 + hi * 8];

    const int krow0 = w * 16 + (lane >> 4);    // +4i
    const int kchunk = lane & 15;
    const int vrow0 = w * 32 + (lane >> 3);    // +8i
    const int vchunk = lane & 7;

    f32x16 o[4] = {};
    float mr = -3e38f, lr = 0.f;

    int nkt = (q0b + 128 + past + 63) >> 6;
    if (nkt > HSF / 64) nkt = HSF / 64;
    const int t0 = (split * nkt) / 3;
    const int t1 = ((split + 1) * nkt) / 3;

    for (int kt = t0; kt < t1; ++kt) {
        const int j0 = kt * 64;
        __syncthreads();
        #pragma unroll
        for (int i = 0; i < 4; ++i) {
            int rk = krow0 + 4 * i;
            GLD16(kx + (size_t)(j0 + rk) * HDH + ((kchunk ^ (rk & 7)) * 8),
                  Ks + w * 2048 + i * 512);
            int rv = vrow0 + 8 * i;
            GLD16(vx + (size_t)rv * HSF + j0 + ((vchunk ^ (rv & 7)) * 8),
                  Vs + w * 2048 + i * 512);
        }
        __syncthreads();

        if (j0 > q0 + 31 + past) continue;

        const char* ksb = (const char*)Ks;
        f32x16 sf0 = {}, sf1 = {};
        const int sw = l31 & 7;
        __builtin_amdgcn_s_setprio(1);
        #pragma unroll
        for (int c = 0; c < 8; ++c) {
            int ch = ((c * 2 + hi) ^ sw) * 16;
            bf16x8 ak0 = *(const bf16x8*)(ksb + l31 * 256 + ch);
            sf0 = mfma32x32(ak0, qf[c], sf0);
            bf16x8 ak1 = *(const bf16x8*)(ksb + (32 + l31) * 256 + ch);
            sf1 = mfma32x32(ak1, qf[c], sf1);
        }
        __builtin_amdgcn_s_setprio(0);

        if (j0 + 63 > q0 + past) {
            #pragma unroll
            for (int r = 0; r < 16; ++r) {
                int ko = (r & 3) + 8 * (r >> 2) + 4 * hi;
                if (j0 + ko > q + past)      sf0[r] = -3e38f;
                if (j0 + 32 + ko > q + past) sf1[r] = -3e38f;
            }
        }
        float pmax = -3e38f;
        #pragma unroll
        for (int r = 0; r < 16; ++r)
            pmax = fmaxf(pmax, fmaxf(sf0[r], sf1[r]));
        pmax = fmaxf(pmax, __shfl_xor(pmax, 32, 64));
        if (!__all((int)(pmax <= mr + 8.f))) {   // defer-max (T13)
            float mnew = fmaxf(mr, pmax);
            float alpha = exp2f(mr - mnew);
            mr = mnew;
            lr *= alpha;
            #pragma unroll
            for (int dt = 0; dt < 4; ++dt) o[dt] *= alpha;
        }
        float ps = 0.f;
        #pragma unroll
        for (int r = 0; r < 16; ++r) {
            sf0[r] = exp2f(sf0[r] - mr);
            sf1[r] = exp2f(sf1[r] - mr);
            ps += sf0[r] + sf1[r];
        }
        ps += __shfl_xor(ps, 32, 64);
        lr += ps;

        u32 wA[8], wB[8];
        #pragma unroll
        for (int g = 0; g < 4; ++g) {
            asm("v_cvt_pk_bf16_f32 %0, %1, %2" : "=v"(wA[2*g])   : "v"(sf0[4*g+0]), "v"(sf0[4*g+1]));
            asm("v_cvt_pk_bf16_f32 %0, %1, %2" : "=v"(wA[2*g+1]) : "v"(sf0[4*g+2]), "v"(sf0[4*g+3]));
            asm("v_cvt_pk_bf16_f32 %0, %1, %2" : "=v"(wB[2*g])   : "v"(sf1[4*g+0]), "v"(sf1[4*g+1]));
            asm("v_cvt_pk_bf16_f32 %0, %1, %2" : "=v"(wB[2*g+1]) : "v"(sf1[4*g+2]), "v"(sf1[4*g+3]));
        }
        pl32swap(wA[0], wA[2]); pl32swap(wA[1], wA[3]);
        pl32swap(wA[4], wA[6]); pl32swap(wA[5], wA[7]);
        pl32swap(wB[0], wB[2]); pl32swap(wB[1], wB[3]);
        pl32swap(wB[4], wB[6]); pl32swap(wB[5], wB[7]);
        union uf { u32 u[4]; bf16x8 v; };
        uf pf0, pf1, pf2, pf3;
        pf0.u[0]=wA[0]; pf0.u[1]=wA[1]; pf0.u[2]=wA[2]; pf0.u[3]=wA[3];
        pf1.u[0]=wA[4]; pf1.u[1]=wA[5]; pf1.u[2]=wA[6]; pf1.u[3]=wA[7];
        pf2.u[0]=wB[0]; pf2.u[1]=wB[1]; pf2.u[2]=wB[2]; pf2.u[3]=wB[3];
        pf3.u[0]=wB[4]; pf3.u[1]=wB[5]; pf3.u[2]=wB[6]; pf3.u[3]=wB[7];

        const char* vsb = (const char*)Vs;
        __builtin_amdgcn_s_setprio(1);
        #pragma unroll
        for (int dt = 0; dt < 4; ++dt) {
            int rb = (dt * 32 + l31) * 128;
            bf16x8 av0 = *(const bf16x8*)(vsb + rb + (((0 + hi) ^ sw) * 16));
            o[dt] = mfma32x32(av0, pf0.v, o[dt]);
            bf16x8 av1 = *(const bf16x8*)(vsb + rb + (((2 + hi) ^ sw) * 16));
            o[dt] = mfma32x32(av1, pf1.v, o[dt]);
            bf16x8 av2 = *(const bf16x8*)(vsb + rb + (((4 + hi) ^ sw) * 16));
            o[dt] = mfma32x32(av2, pf2.v, o[dt]);
            bf16x8 av3 = *(const bf16x8*)(vsb + rb + (((6 + hi) ^ sw) * 16));
            o[dt] = mfma32x32(av3, pf3.v, o[dt]);
        }
        __builtin_amdgcn_s_setprio(0);
    }

    const int qg = bh * HS + q;
    if (hi == 0) {
        pM[split * 32768 + qg] = mr;
        pL[split * 32768 + qg] = lr;
    }
    u16* prow = pO + ((size_t)split * 32768 + qg) * 128;
    #pragma unroll
    for (int dt = 0; dt < 4; ++dt)
        #pragma unroll
        for (int g = 0; g < 4; ++g) {
            ushort4 wv;
            wv.x = f2b(o[dt][4*g+0]);
            wv.y = f2b(o[dt][4*g+1]);
            wv.z = f2b(o[dt][4*g+2]);
            wv.w = f2b(o[dt][4*g+3]);
            *(ushort4*)(prow + dt * 32 + 8 * g + 4 * hi) = wv;
        }
}

// ---------------- combine the three KV-split partials ----------------
__global__ __launch_bounds__(256) void k_combine(
    const u16* __restrict__ pO, const float* __restrict__ pM,
    const float* __restrict__ pL, u16* __restrict__ ctx)
{
    int t = blockIdx.x * 256 + threadIdx.x;      // 0..1048575
    int qg = t >> 5;                             // bh*1024 + q
    int d4 = (t & 31) << 2;
    float m0 = pM[qg], m1 = pM[32768 + qg], m2 = pM[65536 + qg];
    float l0 = pL[qg], l1 = pL[32768 + qg], l2 = pL[65536 + qg];
    float M = fmaxf(fmaxf(m0, m1), m2);
    float a0 = exp2f(m0 - M), a1 = exp2f(m1 - M), a2 = exp2f(m2 - M);
    float inv = 1.f / (a0 * l0 + a1 * l1 + a2 * l2);
    a0 *= inv; a1 *= inv; a2 *= inv;
    ushort4 v0 = *(const ushort4*)(pO + (size_t)qg * 128 + d4);
    ushort4 v1 = *(const ushort4*)(pO + ((size_t)32768 + qg) * 128 + d4);
    ushort4 v2 = *(const ushort4*)(pO + ((size_t)65536 + qg) * 128 + d4);
    int bh = qg >> 10, qq = qg & 1023;
    int b = bh >> 4, hh = bh & 15;
    u16* crow = ctx + ((size_t)(b * HS + qq)) * HD + hh * HDH + d4;
    ushort4 wv;
    wv.x = f2b(a0 * b2f(v0.x) + a1 * b2f(v1.x) + a2 * b2f(v2.x));
    wv.y = f2b(a0 * b2f(v0.y) + a1 * b2f(v1.y) + a2 * b2f(v2.y));
    wv.z = f2b(a0 * b2f(v0.z) + a1 * b2f(v1.z) + a2 * b2f(v2.z));
    wv.w = f2b(a0 * b2f(v0.w) + a1 * b2f(v1.w) + a2 * b2f(v2.w));
    *(ushort4*)crow = wv;
}

// ---------------- launch ----------------
extern "C" void kernel_launch(void* const* d_in, const int* in_sizes, int n_in,
                              void* d_out, int out_size, void* d_ws, size_t ws_size,
                              hipStream_t stream) {
    const float* x   = (const float*)d_in[0];
    const float* kc  = (const float*)d_in[1];
    const float* vc  = (const float*)d_in[2];
    const float* qkv = (const float*)d_in[3];
    const float* wo  = (const float*)d_in[4];
    const int* plp   = (const int*)d_in[5];

    float* out = (float*)d_out;
    float* kf  = out + (size_t)HB * HS * HD;        // k_full
    float* vf  = kf + (size_t)HB * HH * HSF * HDH;  // v_full

    char* ws = (char*)d_ws;
    size_t o1 = (size_t)HM * HD * 2;
    size_t o2 = o1 + (size_t)HD3 * HD * 2;
    size_t o3 = o2 + (size_t)HD * HD * 2;
    size_t o4 = o3 + (size_t)HB * HH * HS * HDH * 2;
    size_t o5 = o4 + (size_t)HB * HH * HSF * HDH * 2;
    size_t o6 = o5 + (size_t)HB * HH * HSF * HDH * 2;
    u16* xb   = (u16*)(ws);
    u16* qkvb = (u16*)(ws + o1);
    u16* wob  = (u16*)(ws + o2);
    u16* qb   = (u16*)(ws + o3);
    u16* kb   = (u16*)(ws + o4);
    u16* vt   = (u16*)(ws + o5);
    u16* ctxb = (u16*)(ws + o6);
    // attention partials alias xb+qkvb (dead after gemm_qkv): 25.95MB <= 33.55MB
    u16* pO   = (u16*)ws;                                  // 3*32768*128 bf16 = 25.2MB
    float* pM = (float*)(ws + (size_t)3 * 32768 * 128 * 2);        // 3*32768 f32
    float* pL = (float*)(ws + (size_t)3 * 32768 * 128 * 2 + 393216);

    k_prep<<<2048, 256, 0, stream>>>(x, xb, HM * HD / 4,
                                     qkv, qkvb, HD3 * HD / 4,
                                     wo, wob, HD * HD / 4,
                                     kc, vc, kf, vf, kb, vt);

    k_gemm_qkv<<<192, 512, 0, stream>>>(
        xb, qkvb, HD, qb, kf, vf, kb, vt);

    k_attn<<<768, 256, 0, stream>>>(qb, kb, vt, pO, pM, pL, plp);
    k_combine<<<4096, 256, 0, stream>>>(pO, pM, pL, ctxb);

    k_gemm_out<<<512, 256, 0, stream>>>(ctxb, wob, HD, out);
}

// Round 21
// 189.290 us; speedup vs baseline: 1.2015x; 1.0235x over previous
//
#include <hip/hip_runtime.h>
#include <cstdint>

#define HB 2
#define HS 1024
#define HSF 2048
#define HH 16
#define HDH 128
#define HD 2048
#define HD3 6144
#define HM 2048  // HB*HS

typedef __attribute__((ext_vector_type(8))) short bf16x8;
typedef __attribute__((ext_vector_type(4))) float f32x4;
typedef __attribute__((ext_vector_type(16))) float f32x16;
typedef unsigned short u16;
typedef unsigned int u32;

__device__ __forceinline__ u16 f2b(float f) {
    union { float f; u32 u; } v; v.f = f;
    u32 u = v.u;
    return (u16)((u + 0x7FFFu + ((u >> 16) & 1u)) >> 16);
}
__device__ __forceinline__ float b2f(u16 h) {
    union { u32 u; float f; } v; v.u = ((u32)h) << 16; return v.f;
}

__device__ __forceinline__ f32x4 mfma16x16(bf16x8 a, bf16x8 b, f32x4 c) {
    return __builtin_amdgcn_mfma_f32_16x16x32_bf16(a, b, c, 0, 0, 0);
}
__device__ __forceinline__ f32x16 mfma32x32(bf16x8 a, bf16x8 b, f32x16 c) {
    return __builtin_amdgcn_mfma_f32_32x32x16_bf16(a, b, c, 0, 0, 0);
}
__device__ __forceinline__ void pl32swap(u32 &a, u32 &b) {
    asm volatile("v_permlane32_swap_b32 %0, %1" : "+v"(a), "+v"(b));
}

#define GLD16(gp, lp) __builtin_amdgcn_global_load_lds( \
    (__attribute__((address_space(1))) void*)(gp), \
    (__attribute__((address_space(3))) void*)(lp), 16, 0, 0)

// ---------------- fused streaming prep (r13-proven) ----------------
__global__ __launch_bounds__(256) void k_prep(
    const float* __restrict__ x,  u16* __restrict__ xb,  int n0,
    const float* __restrict__ qkv, u16* __restrict__ qkvb, int n1,
    const float* __restrict__ wo,  u16* __restrict__ wob, int n2,
    const float* __restrict__ kc, const float* __restrict__ vc,
    float* __restrict__ kf, float* __restrict__ vf,
    u16* __restrict__ kb, u16* __restrict__ vt)
{
    const int bid = blockIdx.x;
    const int tid = threadIdx.x;
    if (bid < 512) {
        __shared__ u16 Lt[128 * 66];      // [dh][s] — stride 66
        int bh = bid >> 4, st = (bid & 15) << 6;
        size_t cbase = (size_t)bh * (HS * HDH) + (size_t)st * HDH;
        size_t fbase = (size_t)bh * (HSF * HDH) + (size_t)st * HDH;
        #pragma unroll
        for (int i = 0; i < 8; ++i) {
            int ci = i * 256 + tid;
            float4 kv = ((const float4*)(kc + cbase))[ci];
            ((float4*)(kf + fbase))[ci] = kv;
            ushort4 k4;
            k4.x = f2b(kv.x); k4.y = f2b(kv.y); k4.z = f2b(kv.z); k4.w = f2b(kv.w);
            ((ushort4*)(kb + fbase))[ci] = k4;
        }
        #pragma unroll
        for (int i = 0; i < 8; ++i) {
            int ci = i * 256 + tid;
            int r = ci >> 5, c = ci & 31;
            float4 vv = ((const float4*)(vc + cbase))[ci];
            ((float4*)(vf + fbase))[ci] = vv;
            int dh = c * 4;
            Lt[(dh + 0) * 66 + r] = f2b(vv.x);
            Lt[(dh + 1) * 66 + r] = f2b(vv.y);
            Lt[(dh + 2) * 66 + r] = f2b(vv.z);
            Lt[(dh + 3) * 66 + r] = f2b(vv.w);
        }
        __syncthreads();
        u16* vtb = vt + (size_t)bh * (HDH * HSF) + st;
        #pragma unroll
        for (int i = 0; i < 4; ++i) {
            int ci = i * 256 + tid;
            int dh = ci >> 3, cs = (ci & 7) * 8;
            const u16* lr = &Lt[dh * 66 + cs];
            ushort4 lo, hi2;
            lo.x = lr[0]; lo.y = lr[1]; lo.z = lr[2]; lo.w = lr[3];
            hi2.x = lr[4]; hi2.y = lr[5]; hi2.z = lr[6]; hi2.w = lr[7];
            u16* dst = vtb + (size_t)dh * HSF + cs;
            *(ushort4*)dst = lo;
            *(ushort4*)(dst + 4) = hi2;
        }
    } else {
        int i = (bid - 512) * 256 + tid;
        const int st_ = ((int)gridDim.x - 512) * 256;
        const int nt = n0 + n1 + n2;
        for (; i < nt; i += st_) {
            const float* s; u16* d; int j = i;
            if (j < n0) { s = x; d = xb; }
            else if (j < n0 + n1) { j -= n0; s = qkv; d = qkvb; }
            else { j -= n0 + n1; s = wo; d = wob; }
            float4 v = ((const float4*)s)[j];
            ushort4 o;
            o.x = f2b(v.x); o.y = f2b(v.y); o.z = f2b(v.z); o.w = f2b(v.w);
            ((ushort4*)d)[j] = o;
        }
    }
}

// ---------------- QKV GEMM: 256x192 tile, BK=64, 2-phase dbuf, FULL CU fill ----
// 256 blocks = 1/CU (r20's 256x256 was 192 blocks = 75% fill; per-CU rate was
// +33% vs 128x128 — this recovers the idle 64 CUs). 8 waves (2x4); per-wave
// 128x48 (frags 8x3). LDS 112KB: 2buf x {A[256][64] 32KB + B[192][64] 24KB}.
// Epilogue is per-element on sector (192 !| 2048): Q/K scatter; V -> vf scatter
// + LDS transpose T[192][256] -> coalesced vt stores (V columns only).
__global__ __launch_bounds__(512, 1) void k_gemm_qkv(
    const u16* __restrict__ A, const u16* __restrict__ Bw, int K,
    u16* __restrict__ qb, float* __restrict__ kf, float* __restrict__ vf,
    u16* __restrict__ kb, u16* __restrict__ vt)
{
    __shared__ __align__(16) u16 SH[57344];   // 112 KB
    const int tid = threadIdx.x;
    const int w = tid >> 6, lane = tid & 63;
    const int wr = w >> 2, wc = w & 3;
    const int lcol = lane & 15, lhi = lane >> 4;
    const int NT = 32;                        // K / 64

    // XCD-bijective: 32 consecutive t per XCD; within XCD, groups of 8 share
    // the same B n-panel (0.75MB, L2-reused 8x) while A streams.
    const int bf = (int)blockIdx.x;           // 0..255
    const int t = (bf & 7) * 32 + (bf >> 3);
    const int m0 = (t & 7) * 256, n0 = (t >> 3) * 192;

    const int srow = tid >> 3;                // 0..63
    const int schunk = tid & 7;

    auto STAGE = [&](int buf, int kt) {
        const int ab = buf * 28672, bb = ab + 16384;
        #pragma unroll
        for (int L = 0; L < 4; ++L) {
            int row = L * 64 + srow;
            int cs = (schunk ^ (row & 7)) * 8;
            GLD16(A + (size_t)(m0 + row) * K + kt * 64 + cs,
                  &SH[ab + L * 4096 + w * 512]);
        }
        #pragma unroll
        for (int L = 0; L < 3; ++L) {
            int row = L * 64 + srow;
            int cs = (schunk ^ (row & 7)) * 8;
            GLD16(Bw + (size_t)(n0 + row) * K + kt * 64 + cs,
                  &SH[bb + L * 4096 + w * 512]);
        }
    };

    f32x4 acc[8][3] = {};

    STAGE(0, 0);
    __syncthreads();

    int cur = 0;
    for (int kt = 0; kt < NT; ++kt) {
        if (kt + 1 < NT) STAGE(cur ^ 1, kt + 1);
        const int ab = cur * 28672, bb = ab + 16384;
        #pragma unroll
        for (int kk = 0; kk < 2; ++kk) {
            bf16x8 af[8], bfr[3];
            #pragma unroll
            for (int i = 0; i < 8; ++i) {
                int r = wr * 128 + i * 16 + lcol;
                int ch = (kk * 4 + lhi) ^ (r & 7);
                af[i] = *(const bf16x8*)&SH[ab + r * 64 + ch * 8];
            }
            #pragma unroll
            for (int j = 0; j < 3; ++j) {
                int r = wc * 48 + j * 16 + lcol;
                int ch = (kk * 4 + lhi) ^ (r & 7);
                bfr[j] = *(const bf16x8*)&SH[bb + r * 64 + ch * 8];
            }
            __builtin_amdgcn_s_setprio(1);
            #pragma unroll
            for (int i = 0; i < 8; ++i)
                #pragma unroll
                for (int j = 0; j < 3; ++j)
                    acc[i][j] = mfma16x16(af[i], bfr[j], acc[i][j]);
            __builtin_amdgcn_s_setprio(0);
        }
        __syncthreads();
        cur ^= 1;
    }

    // ---- per-element-sector epilogue ----
    u16* T = SH;                              // [192 dl][256 sl], granule-swizzled
    #pragma unroll
    for (int i = 0; i < 8; ++i) {
      #pragma unroll
      for (int j = 0; j < 3; ++j) {
        #pragma unroll
        for (int r_ = 0; r_ < 4; ++r_) {
            int sl = wr * 128 + i * 16 + lhi * 4 + r_;    // local m
            int dl = wc * 48 + j * 16 + lcol;             // local n
            int m = m0 + sl, n = n0 + dl;
            float v = acc[i][j][r_];
            int b = m >> 10, s = m & 1023;
            int sec = n >> 11, e = n & 2047;
            int h = e >> 7, dh = e & 127;
            int bh = b * HH + h;
            if (sec == 0) {
                // pre-scale Q by 1/sqrt(dh) * log2(e) for exp2-domain softmax
                qb[((size_t)bh * HS + s) * HDH + dh] = f2b(v * 0.12751742f);
            } else if (sec == 1) {
                size_t idx = ((size_t)bh * HSF + HS + s) * HDH + dh;
                kf[idx] = v; kb[idx] = f2b(v);
            } else {
                vf[((size_t)bh * HSF + HS + s) * HDH + dh] = v;
                T[dl * 256 + (sl ^ ((dl & 31) << 3))] = f2b(v);
            }
        }
      }
    }
    __syncthreads();
    // coalesced vt store for V columns only
    const int b2 = m0 >> 10, s0 = m0 & 1023;
    #pragma unroll
    for (int it = 0; it < 12; ++it) {
        int ci = it * 512 + tid;                 // 0..6143 granules of 8 u16
        int dl = ci >> 5, cs = (ci & 31) * 8;
        int n = n0 + dl;
        if ((n >> 11) != 2) continue;
        const u16* lr = &T[dl * 256 + (cs ^ ((dl & 31) << 3))];
        ushort4 lo = *(const ushort4*)lr;
        ushort4 hi2 = *(const ushort4*)(lr + 4);
        int e = n & 2047;
        int hh = e >> 7, dh = e & 127;
        u16* dst = vt + ((size_t)(b2 * HH + hh) * HDH + dh) * HSF + HS + s0 + cs;
        *(ushort4*)dst = lo;
        *(ushort4*)(dst + 4) = hi2;
    }
}

// ---------------- output GEMM: 128x64 tile, BK=32, 2-phase dbuf (r14-proven) ----------------
__global__ __launch_bounds__(256, 4) void k_gemm_out(
    const u16* __restrict__ A, const u16* __restrict__ Bw, int K,
    float* __restrict__ outf)
{
    __shared__ __align__(16) u16 As[2 * 128 * 32];   // 16 KB
    __shared__ __align__(16) u16 Bs[2 * 64 * 32];    // 8 KB
    const int tid = threadIdx.x;
    const int w = tid >> 6, lane = tid & 63;
    const int wm = w >> 1, wn = w & 1;
    const int lcol = lane & 15, lhi = lane >> 4;

    const int nb = (int)gridDim.x, per = nb >> 3;
    const int bf = (int)blockIdx.x;
    const int t = (bf & 7) * per + (bf >> 3);
    const int m0 = (t & 15) * 128, n0 = (t >> 4) * 64;

    const int srow = lane >> 2;
    const int scol = ((lane & 3) ^ ((lane >> 4) & 2)) * 8;
    const int c0 = w * 2, c1 = w * 2 + 1;
    const u16* Ag0 = A + (size_t)(m0 + c0 * 16 + srow) * K + scol;
    const u16* Ag1 = A + (size_t)(m0 + c1 * 16 + srow) * K + scol;
    const u16* Bg0 = Bw + (size_t)(n0 + w * 16 + srow) * K + scol;

    const int lx = lhi ^ ((lcol >> 2) & 2);

    f32x4 acc[4][2] = {};

    GLD16(Ag0, &As[c0 * 512]);
    GLD16(Ag1, &As[c1 * 512]);
    GLD16(Bg0, &Bs[w * 512]);
    __syncthreads();

    int cur = 0;
    for (int k0 = 0; k0 < K; k0 += 32) {
        if (k0 + 32 < K) {
            GLD16(Ag0 + k0 + 32, &As[(cur ^ 1) * 4096 + c0 * 512]);
            GLD16(Ag1 + k0 + 32, &As[(cur ^ 1) * 4096 + c1 * 512]);
            GLD16(Bg0 + k0 + 32, &Bs[(cur ^ 1) * 2048 + w * 512]);
        }
        const int ca = cur * 4096, cb2 = cur * 2048;
        bf16x8 af[4], bfr[2];
        #pragma unroll
        for (int i = 0; i < 4; ++i)
            af[i] = *(const bf16x8*)&As[ca + (wm * 64 + i * 16 + lcol) * 32 + lx * 8];
        #pragma unroll
        for (int j = 0; j < 2; ++j)
            bfr[j] = *(const bf16x8*)&Bs[cb2 + (wn * 32 + j * 16 + lcol) * 32 + lx * 8];
        __builtin_amdgcn_s_setprio(1);
        #pragma unroll
        for (int i = 0; i < 4; ++i)
            #pragma unroll
            for (int j = 0; j < 2; ++j)
                acc[i][j] = mfma16x16(af[i], bfr[j], acc[i][j]);
        __builtin_amdgcn_s_setprio(0);
        __syncthreads();
        cur ^= 1;
    }

    #pragma unroll
    for (int i = 0; i < 4; ++i)
      #pragma unroll
      for (int j = 0; j < 2; ++j)
        #pragma unroll
        for (int r = 0; r < 4; ++r) {
            int m = m0 + wm * 64 + i * 16 + lhi * 4 + r;
            int n = n0 + wn * 32 + j * 16 + lcol;
            outf[(size_t)m * HD + n] = acc[i][j][r];
        }
}

// ---------------- flash attention: 4 waves x 32 q, LDS tile 64, split-KV x3 ----------------
__global__ __launch_bounds__(256, 3) void k_attn(
    const u16* __restrict__ qb, const u16* __restrict__ kb,
    const u16* __restrict__ vt, u16* __restrict__ pO,
    float* __restrict__ pM, float* __restrict__ pL,
    const int* __restrict__ plp)
{
    __shared__ __align__(16) u16 Ks[64 * 128];   // [key][dh], chunk-swizzled
    __shared__ __align__(16) u16 Vs[128 * 64];   // [dh][key], chunk-swizzled

    const int past = *plp;                 // 1024
    const int tid = threadIdx.x, w = tid >> 6, lane = tid & 63;
    const int l31 = lane & 31, hi = lane >> 5;

    const int bid = blockIdx.x;            // 0..767
    const int orig = (bid & 7) * 96 + (bid >> 3);
    const int split = orig % 3;
    const int rest = orig / 3;             // 0..255
    const int qblk = rest & 7;
    const int bh = rest >> 3;              // 0..31
    const int q0b = qblk * 128;
    const int q0 = q0b + w * 32;           // wave's q base
    const int q = q0 + l31;                // this lane's q row

    const u16* qx = qb + (size_t)bh * HS * HDH;
    const u16* kx = kb + (size_t)bh * HSF * HDH;
    const u16* vx = vt + (size_t)bh * HDH * HSF;

    bf16x8 qf[8];
    #pragma unroll
    for (int c = 0; c < 8; ++c)
        qf[c] = *(const bf16x8*)&qx[(size_t)q * HDH + c * 16 + hi * 8];

    const int krow0 = w * 16 + (lane >> 4);    // +4i
    const int kchunk = lane & 15;
    const int vrow0 = w * 32 + (lane >> 3);    // +8i
    const int vchunk = lane & 7;

    f32x16 o[4] = {};
    float mr = -3e38f, lr = 0.f;

    int nkt = (q0b + 128 + past + 63) >> 6;
    if (nkt > HSF / 64) nkt = HSF / 64;
    const int t0 = (split * nkt) / 3;
    const int t1 = ((split + 1) * nkt) / 3;

    for (int kt = t0; kt < t1; ++kt) {
        const int j0 = kt * 64;
        __syncthreads();
        #pragma unroll
        for (int i = 0; i < 4; ++i) {
            int rk = krow0 + 4 * i;
            GLD16(kx + (size_t)(j0 + rk) * HDH + ((kchunk ^ (rk & 7)) * 8),
                  Ks + w * 2048 + i * 512);
            int rv = vrow0 + 8 * i;
            GLD16(vx + (size_t)rv * HSF + j0 + ((vchunk ^ (rv & 7)) * 8),
                  Vs + w * 2048 + i * 512);
        }
        __syncthreads();

        if (j0 > q0 + 31 + past) continue;

        const char* ksb = (const char*)Ks;
        f32x16 sf0 = {}, sf1 = {};
        const int sw = l31 & 7;
        __builtin_amdgcn_s_setprio(1);
        #pragma unroll
        for (int c = 0; c < 8; ++c) {
            int ch = ((c * 2 + hi) ^ sw) * 16;
            bf16x8 ak0 = *(const bf16x8*)(ksb + l31 * 256 + ch);
            sf0 = mfma32x32(ak0, qf[c], sf0);
            bf16x8 ak1 = *(const bf16x8*)(ksb + (32 + l31) * 256 + ch);
            sf1 = mfma32x32(ak1, qf[c], sf1);
        }
        __builtin_amdgcn_s_setprio(0);

        if (j0 + 63 > q0 + past) {
            #pragma unroll
            for (int r = 0; r < 16; ++r) {
                int ko = (r & 3) + 8 * (r >> 2) + 4 * hi;
                if (j0 + ko > q + past)      sf0[r] = -3e38f;
                if (j0 + 32 + ko > q + past) sf1[r] = -3e38f;
            }
        }
        float pmax = -3e38f;
        #pragma unroll
        for (int r = 0; r < 16; ++r)
            pmax = fmaxf(pmax, fmaxf(sf0[r], sf1[r]));
        pmax = fmaxf(pmax, __shfl_xor(pmax, 32, 64));
        if (!__all((int)(pmax <= mr + 8.f))) {   // defer-max (T13)
            float mnew = fmaxf(mr, pmax);
            float alpha = exp2f(mr - mnew);
            mr = mnew;
            lr *= alpha;
            #pragma unroll
            for (int dt = 0; dt < 4; ++dt) o[dt] *= alpha;
        }
        float ps = 0.f;
        #pragma unroll
        for (int r = 0; r < 16; ++r) {
            sf0[r] = exp2f(sf0[r] - mr);
            sf1[r] = exp2f(sf1[r] - mr);
            ps += sf0[r] + sf1[r];
        }
        ps += __shfl_xor(ps, 32, 64);
        lr += ps;

        u32 wA[8], wB[8];
        #pragma unroll
        for (int g = 0; g < 4; ++g) {
            asm("v_cvt_pk_bf16_f32 %0, %1, %2" : "=v"(wA[2*g])   : "v"(sf0[4*g+0]), "v"(sf0[4*g+1]));
            asm("v_cvt_pk_bf16_f32 %0, %1, %2" : "=v"(wA[2*g+1]) : "v"(sf0[4*g+2]), "v"(sf0[4*g+3]));
            asm("v_cvt_pk_bf16_f32 %0, %1, %2" : "=v"(wB[2*g])   : "v"(sf1[4*g+0]), "v"(sf1[4*g+1]));
            asm("v_cvt_pk_bf16_f32 %0, %1, %2" : "=v"(wB[2*g+1]) : "v"(sf1[4*g+2]), "v"(sf1[4*g+3]));
        }
        pl32swap(wA[0], wA[2]); pl32swap(wA[1], wA[3]);
        pl32swap(wA[4], wA[6]); pl32swap(wA[5], wA[7]);
        pl32swap(wB[0], wB[2]); pl32swap(wB[1], wB[3]);
        pl32swap(wB[4], wB[6]); pl32swap(wB[5], wB[7]);
        union uf { u32 u[4]; bf16x8 v; };
        uf pf0, pf1, pf2, pf3;
        pf0.u[0]=wA[0]; pf0.u[1]=wA[1]; pf0.u[2]=wA[2]; pf0.u[3]=wA[3];
        pf1.u[0]=wA[4]; pf1.u[1]=wA[5]; pf1.u[2]=wA[6]; pf1.u[3]=wA[7];
        pf2.u[0]=wB[0]; pf2.u[1]=wB[1]; pf2.u[2]=wB[2]; pf2.u[3]=wB[3];
        pf3.u[0]=wB[4]; pf3.u[1]=wB[5]; pf3.u[2]=wB[6]; pf3.u[3]=wB[7];

        const char* vsb = (const char*)Vs;
        __builtin_amdgcn_s_setprio(1);
        #pragma unroll
        for (int dt = 0; dt < 4; ++dt) {
            int rb = (dt * 32 + l31) * 128;
            bf16x8 av0 = *(const bf16x8*)(vsb + rb + (((0 + hi) ^ sw) * 16));
            o[dt] = mfma32x32(av0, pf0.v, o[dt]);
            bf16x8 av1 = *(const bf16x8*)(vsb + rb + (((2 + hi) ^ sw) * 16));
            o[dt] = mfma32x32(av1, pf1.v, o[dt]);
            bf16x8 av2 = *(const bf16x8*)(vsb + rb + (((4 + hi) ^ sw) * 16));
            o[dt] = mfma32x32(av2, pf2.v, o[dt]);
            bf16x8 av3 = *(const bf16x8*)(vsb + rb + (((6 + hi) ^ sw) * 16));
            o[dt] = mfma32x32(av3, pf3.v, o[dt]);
        }
        __builtin_amdgcn_s_setprio(0);
    }

    const int qg = bh * HS + q;
    if (hi == 0) {
        pM[split * 32768 + qg] = mr;
        pL[split * 32768 + qg] = lr;
    }
    u16* prow = pO + ((size_t)split * 32768 + qg) * 128;
    #pragma unroll
    for (int dt = 0; dt < 4; ++dt)
        #pragma unroll
        for (int g = 0; g < 4; ++g) {
            ushort4 wv;
            wv.x = f2b(o[dt][4*g+0]);
            wv.y = f2b(o[dt][4*g+1]);
            wv.z = f2b(o[dt][4*g+2]);
            wv.w = f2b(o[dt][4*g+3]);
            *(ushort4*)(prow + dt * 32 + 8 * g + 4 * hi) = wv;
        }
}

// ---------------- combine the three KV-split partials ----------------
__global__ __launch_bounds__(256) void k_combine(
    const u16* __restrict__ pO, const float* __restrict__ pM,
    const float* __restrict__ pL, u16* __restrict__ ctx)
{
    int t = blockIdx.x * 256 + threadIdx.x;      // 0..1048575
    int qg = t >> 5;                             // bh*1024 + q
    int d4 = (t & 31) << 2;
    float m0 = pM[qg], m1 = pM[32768 + qg], m2 = pM[65536 + qg];
    float l0 = pL[qg], l1 = pL[32768 + qg], l2 = pL[65536 + qg];
    float M = fmaxf(fmaxf(m0, m1), m2);
    float a0 = exp2f(m0 - M), a1 = exp2f(m1 - M), a2 = exp2f(m2 - M);
    float inv = 1.f / (a0 * l0 + a1 * l1 + a2 * l2);
    a0 *= inv; a1 *= inv; a2 *= inv;
    ushort4 v0 = *(const ushort4*)(pO + (size_t)qg * 128 + d4);
    ushort4 v1 = *(const ushort4*)(pO + ((size_t)32768 + qg) * 128 + d4);
    ushort4 v2 = *(const ushort4*)(pO + ((size_t)65536 + qg) * 128 + d4);
    int bh = qg >> 10, qq = qg & 1023;
    int b = bh >> 4, hh = bh & 15;
    u16* crow = ctx + ((size_t)(b * HS + qq)) * HD + hh * HDH + d4;
    ushort4 wv;
    wv.x = f2b(a0 * b2f(v0.x) + a1 * b2f(v1.x) + a2 * b2f(v2.x));
    wv.y = f2b(a0 * b2f(v0.y) + a1 * b2f(v1.y) + a2 * b2f(v2.y));
    wv.z = f2b(a0 * b2f(v0.z) + a1 * b2f(v1.z) + a2 * b2f(v2.z));
    wv.w = f2b(a0 * b2f(v0.w) + a1 * b2f(v1.w) + a2 * b2f(v2.w));
    *(ushort4*)crow = wv;
}

// ---------------- launch ----------------
extern "C" void kernel_launch(void* const* d_in, const int* in_sizes, int n_in,
                              void* d_out, int out_size, void* d_ws, size_t ws_size,
                              hipStream_t stream) {
    const float* x   = (const float*)d_in[0];
    const float* kc  = (const float*)d_in[1];
    const float* vc  = (const float*)d_in[2];
    const float* qkv = (const float*)d_in[3];
    const float* wo  = (const float*)d_in[4];
    const int* plp   = (const int*)d_in[5];

    float* out = (float*)d_out;
    float* kf  = out + (size_t)HB * HS * HD;        // k_full
    float* vf  = kf + (size_t)HB * HH * HSF * HDH;  // v_full

    char* ws = (char*)d_ws;
    size_t o1 = (size_t)HM * HD * 2;
    size_t o2 = o1 + (size_t)HD3 * HD * 2;
    size_t o3 = o2 + (size_t)HD * HD * 2;
    size_t o4 = o3 + (size_t)HB * HH * HS * HDH * 2;
    size_t o5 = o4 + (size_t)HB * HH * HSF * HDH * 2;
    size_t o6 = o5 + (size_t)HB * HH * HSF * HDH * 2;
    u16* xb   = (u16*)(ws);
    u16* qkvb = (u16*)(ws + o1);
    u16* wob  = (u16*)(ws + o2);
    u16* qb   = (u16*)(ws + o3);
    u16* kb   = (u16*)(ws + o4);
    u16* vt   = (u16*)(ws + o5);
    u16* ctxb = (u16*)(ws + o6);
    // attention partials alias xb+qkvb (dead after gemm_qkv): 25.95MB <= 33.55MB
    u16* pO   = (u16*)ws;                                  // 3*32768*128 bf16 = 25.2MB
    float* pM = (float*)(ws + (size_t)3 * 32768 * 128 * 2);        // 3*32768 f32
    float* pL = (float*)(ws + (size_t)3 * 32768 * 128 * 2 + 393216);

    k_prep<<<2048, 256, 0, stream>>>(x, xb, HM * HD / 4,
                                     qkv, qkvb, HD3 * HD / 4,
                                     wo, wob, HD / 1 * HD / 4,
                                     kc, vc, kf, vf, kb, vt);

    k_gemm_qkv<<<256, 512, 0, stream>>>(
        xb, qkvb, HD, qb, kf, vf, kb, vt);

    k_attn<<<768, 256, 0, stream>>>(qb, kb, vt, pO, pM, pL, plp);
    k_combine<<<4096, 256, 0, stream>>>(pO, pM, pL, ctxb);

    k_gemm_out<<<512, 256, 0, stream>>>(ctxb, wob, HD, out);
}